// Round 4
// baseline (468.390 us; speedup 1.0000x reference)
//
#include <hip/hip_runtime.h>

#define NN 100000
#define NE 1600000
#define INC 512
#define HID 128
#define OUTC 64
#define BN_EPS 1e-5f

#define SCAN_B 1024
#define NB ((NN + SCAN_B - 1) / SCAN_B)   // 98

typedef __attribute__((ext_vector_type(8))) short short8v;
typedef __attribute__((ext_vector_type(4))) float f32x4;

__device__ __forceinline__ unsigned short f2bf(float f) {
    unsigned u = __float_as_uint(f);
    u += 0x7FFFu + ((u >> 16) & 1u);     // round-to-nearest-even
    return (unsigned short)(u >> 16);
}

// packed f32x2 -> bf16x2 (RNE), D[15:0]=bf16(lo), D[31:16]=bf16(hi)
__device__ __forceinline__ unsigned cvtpk(float lo, float hi) {
    unsigned r;
    asm("v_cvt_pk_bf16_f32 %0, %1, %2" : "=v"(r) : "v"(lo), "v"(hi));
    return r;
}

__device__ __forceinline__ float bflo(unsigned u) { return __uint_as_float(u << 16); }
__device__ __forceinline__ float bfhi(unsigned u) { return __uint_as_float(u & 0xFFFF0000u); }

// ---------------- CSR build ----------------

__global__ void k_init(int* cnt, float* bnsum, float* bnsumsq) {
    int i = blockIdx.x * blockDim.x + threadIdx.x;
    if (i < NN) cnt[i] = 0;
    if (i < HID) { bnsum[i] = 0.f; bnsumsq[i] = 0.f; }
}

__global__ void k_count(const int* __restrict__ col, int* __restrict__ cnt) {
    int e = blockIdx.x * blockDim.x + threadIdx.x;
    if (e < NE) atomicAdd(&cnt[col[e]], 1);
}

__global__ void k_scanA(const int* __restrict__ cnt, int* __restrict__ rowptr, int* __restrict__ bsum) {
    __shared__ int s[SCAN_B];
    int tid = threadIdx.x;
    int i = blockIdx.x * SCAN_B + tid;
    int v = (i < NN) ? cnt[i] : 0;
    s[tid] = v;
    __syncthreads();
    for (int off = 1; off < SCAN_B; off <<= 1) {
        int t = (tid >= off) ? s[tid - off] : 0;
        __syncthreads();
        s[tid] += t;
        __syncthreads();
    }
    if (i < NN) rowptr[i] = s[tid] - v;     // exclusive within chunk
    if (tid == SCAN_B - 1) bsum[blockIdx.x] = s[tid];
}

__global__ void k_scanB(int* bsum) {
    __shared__ int s[NB];
    int tid = threadIdx.x;
    for (int i = tid; i < NB; i += blockDim.x) s[i] = bsum[i];
    __syncthreads();
    if (tid == 0) {
        int run = 0;
        for (int i = 0; i < NB; ++i) { int t = s[i]; s[i] = run; run += t; }
    }
    __syncthreads();
    for (int i = tid; i < NB; i += blockDim.x) bsum[i] = s[i];
}

// cntpos: in = degree count, out = fill cursor (aliased to save ws)
__global__ void k_scanC(int* cntpos, int* rowptr, float* dinv, const int* __restrict__ bsum) {
    int i = blockIdx.x * SCAN_B + threadIdx.x;
    if (i < NN) {
        int deg = cntpos[i];
        float dv = rsqrtf((float)(deg + 1));   // +1 = self-loop
        int v = rowptr[i] + bsum[blockIdx.x];
        rowptr[i] = v;
        dinv[i] = dv;
        cntpos[i] = v;                          // becomes fill cursor
    }
    if (i == 0) rowptr[NN] = NE;
}

__global__ void k_fill(const int* __restrict__ row, const int* __restrict__ col,
                       int* __restrict__ pos, int* __restrict__ csr) {
    int e = blockIdx.x * blockDim.x + threadIdx.x;
    if (e < NE) {
        int c = col[e];
        int p = atomicAdd(&pos[c], 1);
        csr[p] = row[e];
    }
}

// ---------------- W1 -> bf16 transposed [128][512] ----------------

__global__ void k_prepW1(const float* __restrict__ W1, unsigned short* __restrict__ W1T) {
    int i = blockIdx.x * 256 + threadIdx.x;    // 65536 elements
    int k = i >> 7, n = i & 127;
    W1T[(size_t)n * INC + k] = f2bf(W1[i]);
}

// ---------------- GEMM1 (MFMA): h1b[N,128](bf16) = bf16(x)[N,512] @ bf16(W1)[512,128] ----------------
// block: 64 rows x 128 cols, 4 waves; wave w: cols [32w,32w+32)
// MFMA operands swapped (A=W channels, B=x nodes): lane owns 4 consecutive channels
// of one node -> packed 8B bf16 stores.

#define G1BK 64
#define APAD 72   // LDS row stride in shorts (144B -> 2-way bank alias, free)

__global__ __launch_bounds__(256) void k_gemm1m(const float* __restrict__ x,
                                                const unsigned short* __restrict__ W1T,
                                                unsigned short* __restrict__ h1b) {
    __shared__ unsigned short As[64][APAD];
    __shared__ unsigned short Bs[128][APAD];
    int tid = threadIdx.x;
    int m0 = blockIdx.x * 64;
    int w = tid >> 6;
    int lane = tid & 63;

    f32x4 acc[4][2];
    #pragma unroll
    for (int mr = 0; mr < 4; ++mr)
        #pragma unroll
        for (int cb = 0; cb < 2; ++cb) acc[mr][cb] = (f32x4){0.f, 0.f, 0.f, 0.f};

    // A staging: thread -> row tid>>2, k-seg (tid&3)*16
    int ar = tid >> 2;
    int ak = (tid & 3) * 16;
    int arow = m0 + ar; if (arow >= NN) arow = NN - 1;
    const float* xr = x + (size_t)arow * INC;
    // B staging: thread -> col tid>>1, k-seg (tid&1)*32
    int br = tid >> 1;
    int bk = (tid & 1) * 32;
    const unsigned short* wr = W1T + (size_t)br * INC;

    int frow = lane & 15;
    int fk = (lane >> 4) * 8;

    for (int k0 = 0; k0 < INC; k0 += G1BK) {
        #pragma unroll
        for (int q = 0; q < 4; ++q) {
            float4 v = *(const float4*)(xr + k0 + ak + q * 4);
            *(uint2*)&As[ar][ak + q * 4] = make_uint2(cvtpk(v.x, v.y), cvtpk(v.z, v.w));
        }
        #pragma unroll
        for (int q = 0; q < 4; ++q) {
            *(short8v*)&Bs[br][bk + q * 8] = *(const short8v*)(wr + k0 + bk + q * 8);
        }
        __syncthreads();
        #pragma unroll
        for (int kk = 0; kk < G1BK; kk += 32) {
            short8v a[4], b[2];
            #pragma unroll
            for (int mr = 0; mr < 4; ++mr)
                a[mr] = *(const short8v*)&As[16 * mr + frow][kk + fk];   // x nodes (B operand)
            #pragma unroll
            for (int cb = 0; cb < 2; ++cb)
                b[cb] = *(const short8v*)&Bs[32 * w + 16 * cb + frow][kk + fk];  // W channels (A operand)
            #pragma unroll
            for (int mr = 0; mr < 4; ++mr)
                #pragma unroll
                for (int cb = 0; cb < 2; ++cb)
                    acc[mr][cb] = __builtin_amdgcn_mfma_f32_16x16x32_bf16(b[cb], a[mr], acc[mr][cb], 0, 0, 0);
        }
        __syncthreads();
    }
    // D[row=channel][col=node]: node = m0+16mr+(lane&15), channels = 32w+16cb+(lane>>4)*4+j
    int ncol = lane & 15;
    int r4 = (lane >> 4) * 4;
    #pragma unroll
    for (int mr = 0; mr < 4; ++mr) {
        int node = m0 + 16 * mr + ncol;
        if (node < NN) {
            #pragma unroll
            for (int cb = 0; cb < 2; ++cb) {
                int ch = 32 * w + 16 * cb + r4;
                *(uint2*)&h1b[(size_t)node * HID + ch] =
                    make_uint2(cvtpk(acc[mr][cb][0], acc[mr][cb][1]),
                               cvtpk(acc[mr][cb][2], acc[mr][cb][3]));
            }
        }
    }
}

// ---------------- aggregation 1 (128 ch bf16 -> bf16): 1 wave/node ----------------

__global__ __launch_bounds__(256) void k_agg1(const unsigned short* __restrict__ h1b,
                                              const float* __restrict__ dinv,
                                              const int* __restrict__ rowptr, const int* __restrict__ csr,
                                              const float* __restrict__ b1, unsigned* __restrict__ aggb) {
    int node = blockIdx.x * 4 + (threadIdx.x >> 6);
    int lane = threadIdx.x & 63;
    const unsigned* hp = (const unsigned*)h1b;     // 64 uints per row (2 bf16 ch each)
    size_t base = (size_t)node * 64 + lane;
    float di = dinv[node];
    unsigned hv = hp[base];
    float sx = di * di * bflo(hv);
    float sy = di * di * bfhi(hv);
    int s = rowptr[node], e = rowptr[node + 1];
    int j = s;
    for (; j + 4 <= e; j += 4) {
        int r0 = csr[j], r1 = csr[j + 1], r2 = csr[j + 2], r3 = csr[j + 3];
        unsigned v0 = hp[(size_t)r0 * 64 + lane];
        unsigned v1 = hp[(size_t)r1 * 64 + lane];
        unsigned v2 = hp[(size_t)r2 * 64 + lane];
        unsigned v3 = hp[(size_t)r3 * 64 + lane];
        float w0 = di * dinv[r0], w1 = di * dinv[r1];
        float w2 = di * dinv[r2], w3 = di * dinv[r3];
        sx = fmaf(w0, bflo(v0), sx); sy = fmaf(w0, bfhi(v0), sy);
        sx = fmaf(w1, bflo(v1), sx); sy = fmaf(w1, bfhi(v1), sy);
        sx = fmaf(w2, bflo(v2), sx); sy = fmaf(w2, bfhi(v2), sy);
        sx = fmaf(w3, bflo(v3), sx); sy = fmaf(w3, bfhi(v3), sy);
    }
    for (; j < e; ++j) {
        int r = csr[j];
        unsigned v = hp[(size_t)r * 64 + lane];
        float w = di * dinv[r];
        sx = fmaf(w, bflo(v), sx); sy = fmaf(w, bfhi(v), sy);
    }
    float2 bb = ((const float2*)b1)[lane];
    aggb[base] = cvtpk(sx + bb.x, sy + bb.y);
}

// ---------------- BN stats (from bf16 agg) ----------------

__global__ __launch_bounds__(256) void k_bnstats(const unsigned* __restrict__ aggb,
                                                 float* __restrict__ bnsum, float* __restrict__ bnsumsq) {
    __shared__ float4 ss[256], sq[256];
    int g = threadIdx.x & 31;          // 4-channel group: channels 4g..4g+3
    int h = threadIdx.x >> 5;          // 0..7 row offset
    float4 fs = make_float4(0.f, 0.f, 0.f, 0.f);
    float4 fq = make_float4(0.f, 0.f, 0.f, 0.f);
    int rows_per_block = (NN + gridDim.x - 1) / gridDim.x;
    int r0 = blockIdx.x * rows_per_block;
    int r1 = r0 + rows_per_block; if (r1 > NN) r1 = NN;
    for (int r = r0 + h; r < r1; r += 8) {
        uint2 u = *(const uint2*)(aggb + (size_t)r * 64 + 2 * g);
        float a0 = bflo(u.x), a1 = bfhi(u.x), a2 = bflo(u.y), a3 = bfhi(u.y);
        fs.x += a0; fs.y += a1; fs.z += a2; fs.w += a3;
        fq.x += a0 * a0; fq.y += a1 * a1; fq.z += a2 * a2; fq.w += a3 * a3;
    }
    ss[threadIdx.x] = fs; sq[threadIdx.x] = fq;
    __syncthreads();
    if (threadIdx.x < 32) {
        float4 as = ss[threadIdx.x], aq = sq[threadIdx.x];
        #pragma unroll
        for (int k = 1; k < 8; ++k) {
            float4 bs = ss[k * 32 + threadIdx.x], bq = sq[k * 32 + threadIdx.x];
            as.x += bs.x; as.y += bs.y; as.z += bs.z; as.w += bs.w;
            aq.x += bq.x; aq.y += bq.y; aq.z += bq.z; aq.w += bq.w;
        }
        atomicAdd(&bnsum[4 * g + 0], as.x); atomicAdd(&bnsum[4 * g + 1], as.y);
        atomicAdd(&bnsum[4 * g + 2], as.z); atomicAdd(&bnsum[4 * g + 3], as.w);
        atomicAdd(&bnsumsq[4 * g + 0], aq.x); atomicAdd(&bnsumsq[4 * g + 1], aq.y);
        atomicAdd(&bnsumsq[4 * g + 2], aq.z); atomicAdd(&bnsumsq[4 * g + 3], aq.w);
    }
}

__global__ void k_bnfinal(const float* __restrict__ bnsum, const float* __restrict__ bnsumsq,
                          const float* __restrict__ gamma, const float* __restrict__ beta,
                          float* __restrict__ bnscale, float* __restrict__ bnshift) {
    int c = threadIdx.x;
    if (c < HID) {
        float mu = bnsum[c] / (float)NN;
        float var = bnsumsq[c] / (float)NN - mu * mu;
        float sc = gamma[c] * rsqrtf(var + BN_EPS);
        bnscale[c] = sc;
        bnshift[c] = beta[c] - mu * sc;
    }
}

// ---------------- GEMM2: h2b[N,64](bf16) = relu(bn(aggb)) @ W2[128,64], BN+ReLU fused ----------------

__global__ __launch_bounds__(256) void k_gemm2(const unsigned* __restrict__ aggb, const float* __restrict__ W2,
                                               const float* __restrict__ bnscale, const float* __restrict__ bnshift,
                                               unsigned short* __restrict__ h2b) {
    __shared__ float As2[32][66];
    __shared__ float Bs2[32][OUTC];
    int tid = threadIdx.x;
    int m0 = blockIdx.x * 64;
    int tx = tid & 15, ty = tid >> 4;
    float acc[4][4];
    #pragma unroll
    for (int r = 0; r < 4; ++r)
        #pragma unroll
        for (int c = 0; c < 4; ++c) acc[r][c] = 0.f;

    int am = tid >> 3;          // 0..31
    int ak = (tid & 7) * 4;     // 0..28
    int bk = tid >> 4;          // 0..15
    int bc = (tid & 15) * 4;    // 0..60

    for (int k0 = 0; k0 < HID; k0 += 32) {
        #pragma unroll
        for (int h = 0; h < 2; ++h) {
            int m = am + h * 32;
            int rowi = m0 + m; if (rowi >= NN) rowi = NN - 1;
            uint2 u = *(const uint2*)(aggb + (size_t)rowi * 64 + ((k0 + ak) >> 1));
            float4 sc = *(const float4*)(bnscale + k0 + ak);
            float4 sh = *(const float4*)(bnshift + k0 + ak);
            As2[ak + 0][m] = fmaxf(fmaf(bflo(u.x), sc.x, sh.x), 0.f);
            As2[ak + 1][m] = fmaxf(fmaf(bfhi(u.x), sc.y, sh.y), 0.f);
            As2[ak + 2][m] = fmaxf(fmaf(bflo(u.y), sc.z, sh.z), 0.f);
            As2[ak + 3][m] = fmaxf(fmaf(bfhi(u.y), sc.w, sh.w), 0.f);
        }
        #pragma unroll
        for (int h = 0; h < 2; ++h) {
            int k = bk + h * 16;
            *(float4*)&Bs2[k][bc] = *(const float4*)(W2 + (size_t)(k0 + k) * OUTC + bc);
        }
        __syncthreads();
        #pragma unroll
        for (int k = 0; k < 32; ++k) {
            float a[4];
            #pragma unroll
            for (int r = 0; r < 4; ++r) a[r] = As2[k][ty * 4 + r];
            float4 b = *(const float4*)&Bs2[k][tx * 4];
            #pragma unroll
            for (int r = 0; r < 4; ++r) {
                acc[r][0] = fmaf(a[r], b.x, acc[r][0]);
                acc[r][1] = fmaf(a[r], b.y, acc[r][1]);
                acc[r][2] = fmaf(a[r], b.z, acc[r][2]);
                acc[r][3] = fmaf(a[r], b.w, acc[r][3]);
            }
        }
        __syncthreads();
    }
    #pragma unroll
    for (int r = 0; r < 4; ++r) {
        int m = m0 + ty * 4 + r;
        if (m < NN) {
            *(uint2*)(h2b + (size_t)m * OUTC + tx * 4) =
                make_uint2(cvtpk(acc[r][0], acc[r][1]), cvtpk(acc[r][2], acc[r][3]));
        }
    }
}

// ---------------- aggregation 2 (64 ch bf16): 1 wave/node, lane-halves alternate edges ----------------

__global__ __launch_bounds__(256) void k_agg2(const unsigned short* __restrict__ h2b,
                                              const float* __restrict__ dinv,
                                              const int* __restrict__ rowptr, const int* __restrict__ csr,
                                              const float* __restrict__ b2, float* __restrict__ out) {
    int node = blockIdx.x * 4 + (threadIdx.x >> 6);
    int lane = threadIdx.x & 63;
    int l32 = lane & 31;
    const unsigned* hp = (const unsigned*)h2b;     // 32 uints per row (2 bf16 ch each)
    float di = dinv[node];
    float sx = 0.f, sy = 0.f;
    if (lane < 32) {
        unsigned u = hp[(size_t)node * 32 + l32];
        sx = di * di * bflo(u);
        sy = di * di * bfhi(u);
    }
    int s = rowptr[node], e = rowptr[node + 1];
    int j = s + (lane >> 5);
    for (; j + 2 < e; j += 4) {
        int r0 = csr[j], r1 = csr[j + 2];
        unsigned v0 = hp[(size_t)r0 * 32 + l32];
        unsigned v1 = hp[(size_t)r1 * 32 + l32];
        float w0 = di * dinv[r0], w1 = di * dinv[r1];
        sx = fmaf(w0, bflo(v0), sx); sy = fmaf(w0, bfhi(v0), sy);
        sx = fmaf(w1, bflo(v1), sx); sy = fmaf(w1, bfhi(v1), sy);
    }
    if (j < e) {
        int r = csr[j];
        unsigned v = hp[(size_t)r * 32 + l32];
        float w = di * dinv[r];
        sx = fmaf(w, bflo(v), sx); sy = fmaf(w, bfhi(v), sy);
    }
    // combine the two lane-halves (each holds partials for the same channel pair)
    sx += __shfl_xor(sx, 32);
    sy += __shfl_xor(sy, 32);
    if (lane < 32) {
        float2 bb = ((const float2*)b2)[l32];
        ((float2*)out)[(size_t)node * 32 + l32] = make_float2(sx + bb.x, sy + bb.y);
    }
}

// ---------------- launch ----------------

extern "C" void kernel_launch(void* const* d_in, const int* in_sizes, int n_in,
                              void* d_out, int out_size, void* d_ws, size_t ws_size,
                              hipStream_t stream) {
    const float* x     = (const float*)d_in[0];
    const int*   ei    = (const int*)d_in[1];
    const float* W1    = (const float*)d_in[2];
    const float* b1    = (const float*)d_in[3];
    const float* gamma = (const float*)d_in[4];
    const float* beta  = (const float*)d_in[5];
    const float* W2    = (const float*)d_in[6];
    const float* b2    = (const float*)d_in[7];
    const int* row = ei;          // edge_index[0]
    const int* col = ei + NE;     // edge_index[1]
    float* out = (float*)d_out;

    char* wp = (char*)d_ws;
    auto alloc = [&](size_t bytes) -> void* {
        void* p = (void*)wp;
        wp += (bytes + 255) & ~(size_t)255;
        return p;
    };
    unsigned short* h1b = (unsigned short*)alloc((size_t)NN * HID * 2);
    unsigned* aggb = (unsigned*)alloc((size_t)NN * HID * 2);
    unsigned short* h2b = (unsigned short*)alloc((size_t)NN * OUTC * 2);
    float* dinv    = (float*)alloc((size_t)NN * 4);
    float* bnsum   = (float*)alloc(HID * 4);
    float* bnsumsq = (float*)alloc(HID * 4);
    float* bnscale = (float*)alloc(HID * 4);
    float* bnshift = (float*)alloc(HID * 4);
    int*   rowptr  = (int*)alloc((size_t)(NN + 1) * 4);
    int*   cntpos  = (int*)alloc((size_t)NN * 4);
    int*   bsum    = (int*)alloc(NB * 4);
    int*   csr     = (int*)alloc((size_t)NE * 4);
    unsigned short* W1T = (unsigned short*)alloc((size_t)HID * INC * 2);

    hipLaunchKernelGGL(k_init,  dim3((NN + 255) / 256), dim3(256), 0, stream, cntpos, bnsum, bnsumsq);
    hipLaunchKernelGGL(k_count, dim3((NE + 255) / 256), dim3(256), 0, stream, col, cntpos);
    hipLaunchKernelGGL(k_scanA, dim3(NB), dim3(SCAN_B), 0, stream, cntpos, rowptr, bsum);
    hipLaunchKernelGGL(k_scanB, dim3(1), dim3(128), 0, stream, bsum);
    hipLaunchKernelGGL(k_scanC, dim3(NB), dim3(SCAN_B), 0, stream, cntpos, rowptr, dinv, bsum);
    hipLaunchKernelGGL(k_fill,  dim3((NE + 255) / 256), dim3(256), 0, stream, row, col, cntpos, csr);
    hipLaunchKernelGGL(k_prepW1, dim3(256), dim3(256), 0, stream, W1, W1T);
    hipLaunchKernelGGL(k_gemm1m, dim3((NN + 63) / 64), dim3(256), 0, stream, x, W1T, h1b);
    hipLaunchKernelGGL(k_agg1,  dim3(NN / 4), dim3(256), 0, stream, h1b, dinv, rowptr, csr, b1, aggb);
    hipLaunchKernelGGL(k_bnstats, dim3(256), dim3(256), 0, stream, aggb, bnsum, bnsumsq);
    hipLaunchKernelGGL(k_bnfinal, dim3(1), dim3(128), 0, stream, bnsum, bnsumsq, gamma, beta, bnscale, bnshift);
    hipLaunchKernelGGL(k_gemm2, dim3((NN + 63) / 64), dim3(256), 0, stream, aggb, W2, bnscale, bnshift, h2b);
    hipLaunchKernelGGL(k_agg2,  dim3(NN / 4), dim3(256), 0, stream, h2b, dinv, rowptr, csr, b2, out);
}

// Round 5
// 346.889 us; speedup vs baseline: 1.3503x; 1.3503x over previous
//
#include <hip/hip_runtime.h>

#define NN 100000
#define NE 1600000
#define INC 512
#define HID 128
#define OUTC 64
#define BN_EPS 1e-5f

#define GS_B 1024
#define NSCB 98                   // scan blocks for both NN and NBUK*NBLK (<=100352)

#define NBLK 256
#define CHUNK (NE / NBLK)         // 6250 exactly
#define BSH 8
#define NBUK ((NN + 255) >> 8)    // 391 buckets of 256 nodes

typedef __attribute__((ext_vector_type(8))) short short8v;
typedef __attribute__((ext_vector_type(4))) float f32x4;

__device__ __forceinline__ unsigned short f2bf(float f) {
    unsigned u = __float_as_uint(f);
    u += 0x7FFFu + ((u >> 16) & 1u);     // round-to-nearest-even
    return (unsigned short)(u >> 16);
}

// packed f32x2 -> bf16x2 (RNE), D[15:0]=bf16(lo), D[31:16]=bf16(hi)
__device__ __forceinline__ unsigned cvtpk(float lo, float hi) {
    unsigned r;
    asm("v_cvt_pk_bf16_f32 %0, %1, %2" : "=v"(r) : "v"(lo), "v"(hi));
    return r;
}

__device__ __forceinline__ float bflo(unsigned u) { return __uint_as_float(u << 16); }
__device__ __forceinline__ float bfhi(unsigned u) { return __uint_as_float(u & 0xFFFF0000u); }

// ---------------- init (BN accumulators only) ----------------

__global__ void k_init(float* bnsum, float* bnsumsq) {
    int i = threadIdx.x;
    if (i < HID) { bnsum[i] = 0.f; bnsumsq[i] = 0.f; }
}

// ---------------- bucketed CSR build ----------------

__global__ __launch_bounds__(256) void k_bhist(const int* __restrict__ col, int* __restrict__ bhist) {
    __shared__ int lc[NBUK];
    int tid = threadIdx.x, blk = blockIdx.x;
    for (int i = tid; i < NBUK; i += 256) lc[i] = 0;
    __syncthreads();
    int s = blk * CHUNK, e = s + CHUNK;
    for (int j = s + tid; j < e; j += 256)
        atomicAdd(&lc[col[j] >> BSH], 1);
    __syncthreads();
    for (int i = tid; i < NBUK; i += 256)
        bhist[i * NBLK + blk] = lc[i];
}

// generic scan: per-block exclusive prefix (in-place safe) + block totals
__global__ void k_gscanA(const int* __restrict__ src, int* __restrict__ dst,
                         int* __restrict__ bsum, int n) {
    __shared__ int s[GS_B];
    int tid = threadIdx.x;
    int i = blockIdx.x * GS_B + tid;
    int v = (i < n) ? src[i] : 0;
    s[tid] = v;
    __syncthreads();
    for (int off = 1; off < GS_B; off <<= 1) {
        int t = (tid >= off) ? s[tid - off] : 0;
        __syncthreads();
        s[tid] += t;
        __syncthreads();
    }
    if (i < n) dst[i] = s[tid] - v;
    if (tid == GS_B - 1) bsum[blockIdx.x] = s[tid];
}

__global__ void k_gscanB(int* bsum, int nb) {
    __shared__ int s[256];
    int tid = threadIdx.x;
    for (int i = tid; i < nb; i += blockDim.x) s[i] = bsum[i];
    __syncthreads();
    if (tid == 0) {
        int run = 0;
        for (int i = 0; i < nb; ++i) { int t = s[i]; s[i] = run; run += t; }
    }
    __syncthreads();
    for (int i = tid; i < nb; i += blockDim.x) bsum[i] = s[i];
}

__global__ __launch_bounds__(256) void k_bpart(const int* __restrict__ row, const int* __restrict__ col,
                                               const int* __restrict__ sb, const int* __restrict__ sbsum,
                                               int2* __restrict__ ebuk) {
    __shared__ int lcur[NBUK];
    int tid = threadIdx.x, blk = blockIdx.x;
    for (int i = tid; i < NBUK; i += 256) {
        int idx = i * NBLK + blk;
        lcur[i] = sb[idx] + sbsum[idx >> 10];
    }
    __syncthreads();
    int s = blk * CHUNK, e = s + CHUNK;
    for (int j = s + tid; j < e; j += 256) {
        int r = row[j], c = col[j];
        int p = atomicAdd(&lcur[c >> BSH], 1);
        ebuk[p] = make_int2(r, c);
    }
}

__global__ __launch_bounds__(256) void k_ncount(const int2* __restrict__ ebuk,
                                                const int* __restrict__ sb, const int* __restrict__ sbsum,
                                                int* __restrict__ cnt) {
    __shared__ int lc[256];
    int b = blockIdx.x, tid = threadIdx.x;
    lc[tid] = 0;
    __syncthreads();
    int i0 = b * NBLK;
    int s = sb[i0] + sbsum[i0 >> 10];
    int e2 = (b + 1 < NBUK) ? (sb[i0 + NBLK] + sbsum[(i0 + NBLK) >> 10]) : NE;
    int node0 = b << BSH;
    for (int j = s + tid; j < e2; j += 256)
        atomicAdd(&lc[ebuk[j].y - node0], 1);
    __syncthreads();
    int node = node0 + tid;
    if (node < NN) cnt[node] = lc[tid];
}

__global__ void k_scanC2(const int* __restrict__ cnt, int* __restrict__ rowptr,
                         float* __restrict__ dinv, const int* __restrict__ bsum) {
    int i = blockIdx.x * GS_B + threadIdx.x;
    if (i < NN) {
        rowptr[i] += bsum[blockIdx.x];
        dinv[i] = rsqrtf((float)(cnt[i] + 1));   // +1 = self-loop
    }
    if (i == 0) rowptr[NN] = NE;
}

__global__ __launch_bounds__(256) void k_bfill(const int2* __restrict__ ebuk,
                                               const int* __restrict__ sb, const int* __restrict__ sbsum,
                                               const int* __restrict__ rowptr, const float* __restrict__ dinv,
                                               int2* __restrict__ csr) {
    __shared__ int lcur[256];
    __shared__ float ld[256];
    int b = blockIdx.x, tid = threadIdx.x;
    int node0 = b << BSH;
    int node = node0 + tid;
    lcur[tid] = (node < NN) ? rowptr[node] : 0;
    ld[tid] = (node < NN) ? dinv[node] : 0.f;
    __syncthreads();
    int i0 = b * NBLK;
    int s = sb[i0] + sbsum[i0 >> 10];
    int e2 = (b + 1 < NBUK) ? (sb[i0 + NBLK] + sbsum[(i0 + NBLK) >> 10]) : NE;
    for (int j = s + tid; j < e2; j += 256) {
        int2 rc = ebuk[j];
        int li = rc.y - node0;
        float w = ld[li] * dinv[rc.x];
        int p = atomicAdd(&lcur[li], 1);
        csr[p] = make_int2(rc.x, __float_as_int(w));
    }
}

// ---------------- W1 -> bf16 transposed [128][512] ----------------

__global__ void k_prepW1(const float* __restrict__ W1, unsigned short* __restrict__ W1T) {
    int i = blockIdx.x * 256 + threadIdx.x;    // 65536 elements
    int k = i >> 7, n = i & 127;
    W1T[(size_t)n * INC + k] = f2bf(W1[i]);
}

// ---------------- GEMM1 (MFMA): h1b[N,128](bf16) = bf16(x)[N,512] @ bf16(W1)[512,128] ----------------

#define G1BK 64
#define APAD 72   // LDS row stride in shorts (144B -> 2-way bank alias, free)

__global__ __launch_bounds__(256) void k_gemm1m(const float* __restrict__ x,
                                                const unsigned short* __restrict__ W1T,
                                                unsigned short* __restrict__ h1b) {
    __shared__ unsigned short As[64][APAD];
    __shared__ unsigned short Bs[128][APAD];
    int tid = threadIdx.x;
    int m0 = blockIdx.x * 64;
    int w = tid >> 6;
    int lane = tid & 63;

    f32x4 acc[4][2];
    #pragma unroll
    for (int mr = 0; mr < 4; ++mr)
        #pragma unroll
        for (int cb = 0; cb < 2; ++cb) acc[mr][cb] = (f32x4){0.f, 0.f, 0.f, 0.f};

    int ar = tid >> 2;
    int ak = (tid & 3) * 16;
    int arow = m0 + ar; if (arow >= NN) arow = NN - 1;
    const float* xr = x + (size_t)arow * INC;
    int br = tid >> 1;
    int bk = (tid & 1) * 32;
    const unsigned short* wr = W1T + (size_t)br * INC;

    int frow = lane & 15;
    int fk = (lane >> 4) * 8;

    for (int k0 = 0; k0 < INC; k0 += G1BK) {
        #pragma unroll
        for (int q = 0; q < 4; ++q) {
            float4 v = *(const float4*)(xr + k0 + ak + q * 4);
            *(uint2*)&As[ar][ak + q * 4] = make_uint2(cvtpk(v.x, v.y), cvtpk(v.z, v.w));
        }
        #pragma unroll
        for (int q = 0; q < 4; ++q) {
            *(short8v*)&Bs[br][bk + q * 8] = *(const short8v*)(wr + k0 + bk + q * 8);
        }
        __syncthreads();
        #pragma unroll
        for (int kk = 0; kk < G1BK; kk += 32) {
            short8v a[4], b[2];
            #pragma unroll
            for (int mr = 0; mr < 4; ++mr)
                a[mr] = *(const short8v*)&As[16 * mr + frow][kk + fk];   // x nodes (B operand)
            #pragma unroll
            for (int cb = 0; cb < 2; ++cb)
                b[cb] = *(const short8v*)&Bs[32 * w + 16 * cb + frow][kk + fk];  // W channels (A operand)
            #pragma unroll
            for (int mr = 0; mr < 4; ++mr)
                #pragma unroll
                for (int cb = 0; cb < 2; ++cb)
                    acc[mr][cb] = __builtin_amdgcn_mfma_f32_16x16x32_bf16(b[cb], a[mr], acc[mr][cb], 0, 0, 0);
        }
        __syncthreads();
    }
    int ncol = lane & 15;
    int r4 = (lane >> 4) * 4;
    #pragma unroll
    for (int mr = 0; mr < 4; ++mr) {
        int node = m0 + 16 * mr + ncol;
        if (node < NN) {
            #pragma unroll
            for (int cb = 0; cb < 2; ++cb) {
                int ch = 32 * w + 16 * cb + r4;
                *(uint2*)&h1b[(size_t)node * HID + ch] =
                    make_uint2(cvtpk(acc[mr][cb][0], acc[mr][cb][1]),
                               cvtpk(acc[mr][cb][2], acc[mr][cb][3]));
            }
        }
    }
}

// ---------------- aggregation 1 (128 ch bf16 -> bf16): 1 wave/node, stored weights ----------------

__global__ __launch_bounds__(256) void k_agg1(const unsigned short* __restrict__ h1b,
                                              const float* __restrict__ dinv,
                                              const int* __restrict__ rowptr, const int2* __restrict__ csr,
                                              const float* __restrict__ b1, unsigned* __restrict__ aggb) {
    int node = blockIdx.x * 4 + (threadIdx.x >> 6);
    int lane = threadIdx.x & 63;
    const unsigned* hp = (const unsigned*)h1b;     // 64 uints per row (2 bf16 ch each)
    size_t base = (size_t)node * 64 + lane;
    float di = dinv[node];
    unsigned hv = hp[base];
    float sx = di * di * bflo(hv);
    float sy = di * di * bfhi(hv);
    int s = rowptr[node], e = rowptr[node + 1];
    int j = s;
    for (; j + 4 <= e; j += 4) {
        int2 c0 = csr[j], c1 = csr[j + 1], c2 = csr[j + 2], c3 = csr[j + 3];
        unsigned v0 = hp[(size_t)c0.x * 64 + lane];
        unsigned v1 = hp[(size_t)c1.x * 64 + lane];
        unsigned v2 = hp[(size_t)c2.x * 64 + lane];
        unsigned v3 = hp[(size_t)c3.x * 64 + lane];
        float w0 = __int_as_float(c0.y), w1 = __int_as_float(c1.y);
        float w2 = __int_as_float(c2.y), w3 = __int_as_float(c3.y);
        sx = fmaf(w0, bflo(v0), sx); sy = fmaf(w0, bfhi(v0), sy);
        sx = fmaf(w1, bflo(v1), sx); sy = fmaf(w1, bfhi(v1), sy);
        sx = fmaf(w2, bflo(v2), sx); sy = fmaf(w2, bfhi(v2), sy);
        sx = fmaf(w3, bflo(v3), sx); sy = fmaf(w3, bfhi(v3), sy);
    }
    for (; j < e; ++j) {
        int2 c = csr[j];
        unsigned v = hp[(size_t)c.x * 64 + lane];
        float w = __int_as_float(c.y);
        sx = fmaf(w, bflo(v), sx); sy = fmaf(w, bfhi(v), sy);
    }
    float2 bb = ((const float2*)b1)[lane];
    aggb[base] = cvtpk(sx + bb.x, sy + bb.y);
}

// ---------------- BN stats (from bf16 agg) ----------------

__global__ __launch_bounds__(256) void k_bnstats(const unsigned* __restrict__ aggb,
                                                 float* __restrict__ bnsum, float* __restrict__ bnsumsq) {
    __shared__ float4 ss[256], sq[256];
    int g = threadIdx.x & 31;          // 4-channel group: channels 4g..4g+3
    int h = threadIdx.x >> 5;          // 0..7 row offset
    float4 fs = make_float4(0.f, 0.f, 0.f, 0.f);
    float4 fq = make_float4(0.f, 0.f, 0.f, 0.f);
    int rows_per_block = (NN + gridDim.x - 1) / gridDim.x;
    int r0 = blockIdx.x * rows_per_block;
    int r1 = r0 + rows_per_block; if (r1 > NN) r1 = NN;
    for (int r = r0 + h; r < r1; r += 8) {
        uint2 u = *(const uint2*)(aggb + (size_t)r * 64 + 2 * g);
        float a0 = bflo(u.x), a1 = bfhi(u.x), a2 = bflo(u.y), a3 = bfhi(u.y);
        fs.x += a0; fs.y += a1; fs.z += a2; fs.w += a3;
        fq.x += a0 * a0; fq.y += a1 * a1; fq.z += a2 * a2; fq.w += a3 * a3;
    }
    ss[threadIdx.x] = fs; sq[threadIdx.x] = fq;
    __syncthreads();
    if (threadIdx.x < 32) {
        float4 as = ss[threadIdx.x], aq = sq[threadIdx.x];
        #pragma unroll
        for (int k = 1; k < 8; ++k) {
            float4 bs = ss[k * 32 + threadIdx.x], bq = sq[k * 32 + threadIdx.x];
            as.x += bs.x; as.y += bs.y; as.z += bs.z; as.w += bs.w;
            aq.x += bq.x; aq.y += bq.y; aq.z += bq.z; aq.w += bq.w;
        }
        atomicAdd(&bnsum[4 * g + 0], as.x); atomicAdd(&bnsum[4 * g + 1], as.y);
        atomicAdd(&bnsum[4 * g + 2], as.z); atomicAdd(&bnsum[4 * g + 3], as.w);
        atomicAdd(&bnsumsq[4 * g + 0], aq.x); atomicAdd(&bnsumsq[4 * g + 1], aq.y);
        atomicAdd(&bnsumsq[4 * g + 2], aq.z); atomicAdd(&bnsumsq[4 * g + 3], aq.w);
    }
}

__global__ void k_bnfinal(const float* __restrict__ bnsum, const float* __restrict__ bnsumsq,
                          const float* __restrict__ gamma, const float* __restrict__ beta,
                          float* __restrict__ bnscale, float* __restrict__ bnshift) {
    int c = threadIdx.x;
    if (c < HID) {
        float mu = bnsum[c] / (float)NN;
        float var = bnsumsq[c] / (float)NN - mu * mu;
        float sc = gamma[c] * rsqrtf(var + BN_EPS);
        bnscale[c] = sc;
        bnshift[c] = beta[c] - mu * sc;
    }
}

// ---------------- GEMM2: h2b[N,64](bf16) = relu(bn(aggb)) @ W2[128,64], BN+ReLU fused ----------------

__global__ __launch_bounds__(256) void k_gemm2(const unsigned* __restrict__ aggb, const float* __restrict__ W2,
                                               const float* __restrict__ bnscale, const float* __restrict__ bnshift,
                                               unsigned short* __restrict__ h2b) {
    __shared__ float As2[32][66];
    __shared__ float Bs2[32][OUTC];
    int tid = threadIdx.x;
    int m0 = blockIdx.x * 64;
    int tx = tid & 15, ty = tid >> 4;
    float acc[4][4];
    #pragma unroll
    for (int r = 0; r < 4; ++r)
        #pragma unroll
        for (int c = 0; c < 4; ++c) acc[r][c] = 0.f;

    int am = tid >> 3;          // 0..31
    int ak = (tid & 7) * 4;     // 0..28
    int bk = tid >> 4;          // 0..15
    int bc = (tid & 15) * 4;    // 0..60

    for (int k0 = 0; k0 < HID; k0 += 32) {
        #pragma unroll
        for (int h = 0; h < 2; ++h) {
            int m = am + h * 32;
            int rowi = m0 + m; if (rowi >= NN) rowi = NN - 1;
            uint2 u = *(const uint2*)(aggb + (size_t)rowi * 64 + ((k0 + ak) >> 1));
            float4 sc = *(const float4*)(bnscale + k0 + ak);
            float4 sh = *(const float4*)(bnshift + k0 + ak);
            As2[ak + 0][m] = fmaxf(fmaf(bflo(u.x), sc.x, sh.x), 0.f);
            As2[ak + 1][m] = fmaxf(fmaf(bfhi(u.x), sc.y, sh.y), 0.f);
            As2[ak + 2][m] = fmaxf(fmaf(bflo(u.y), sc.z, sh.z), 0.f);
            As2[ak + 3][m] = fmaxf(fmaf(bfhi(u.y), sc.w, sh.w), 0.f);
        }
        #pragma unroll
        for (int h = 0; h < 2; ++h) {
            int k = bk + h * 16;
            *(float4*)&Bs2[k][bc] = *(const float4*)(W2 + (size_t)(k0 + k) * OUTC + bc);
        }
        __syncthreads();
        #pragma unroll
        for (int k = 0; k < 32; ++k) {
            float a[4];
            #pragma unroll
            for (int r = 0; r < 4; ++r) a[r] = As2[k][ty * 4 + r];
            float4 b = *(const float4*)&Bs2[k][tx * 4];
            #pragma unroll
            for (int r = 0; r < 4; ++r) {
                acc[r][0] = fmaf(a[r], b.x, acc[r][0]);
                acc[r][1] = fmaf(a[r], b.y, acc[r][1]);
                acc[r][2] = fmaf(a[r], b.z, acc[r][2]);
                acc[r][3] = fmaf(a[r], b.w, acc[r][3]);
            }
        }
        __syncthreads();
    }
    #pragma unroll
    for (int r = 0; r < 4; ++r) {
        int m = m0 + ty * 4 + r;
        if (m < NN) {
            *(uint2*)(h2b + (size_t)m * OUTC + tx * 4) =
                make_uint2(cvtpk(acc[r][0], acc[r][1]), cvtpk(acc[r][2], acc[r][3]));
        }
    }
}

// ---------------- aggregation 2 (64 ch bf16): 1 wave/node, lane-halves alternate edges ----------------

__global__ __launch_bounds__(256) void k_agg2(const unsigned short* __restrict__ h2b,
                                              const float* __restrict__ dinv,
                                              const int* __restrict__ rowptr, const int2* __restrict__ csr,
                                              const float* __restrict__ b2, float* __restrict__ out) {
    int node = blockIdx.x * 4 + (threadIdx.x >> 6);
    int lane = threadIdx.x & 63;
    int l32 = lane & 31;
    const unsigned* hp = (const unsigned*)h2b;     // 32 uints per row (2 bf16 ch each)
    float di = dinv[node];
    float sx = 0.f, sy = 0.f;
    if (lane < 32) {
        unsigned u = hp[(size_t)node * 32 + l32];
        sx = di * di * bflo(u);
        sy = di * di * bfhi(u);
    }
    int s = rowptr[node], e = rowptr[node + 1];
    int j = s + (lane >> 5);
    for (; j + 2 < e; j += 4) {
        int2 c0 = csr[j], c1 = csr[j + 2];
        unsigned v0 = hp[(size_t)c0.x * 32 + l32];
        unsigned v1 = hp[(size_t)c1.x * 32 + l32];
        float w0 = __int_as_float(c0.y), w1 = __int_as_float(c1.y);
        sx = fmaf(w0, bflo(v0), sx); sy = fmaf(w0, bfhi(v0), sy);
        sx = fmaf(w1, bflo(v1), sx); sy = fmaf(w1, bfhi(v1), sy);
    }
    if (j < e) {
        int2 c = csr[j];
        unsigned v = hp[(size_t)c.x * 32 + l32];
        float w = __int_as_float(c.y);
        sx = fmaf(w, bflo(v), sx); sy = fmaf(w, bfhi(v), sy);
    }
    sx += __shfl_xor(sx, 32);
    sy += __shfl_xor(sy, 32);
    if (lane < 32) {
        float2 bb = ((const float2*)b2)[l32];
        ((float2*)out)[(size_t)node * 32 + l32] = make_float2(sx + bb.x, sy + bb.y);
    }
}

// ---------------- launch ----------------

extern "C" void kernel_launch(void* const* d_in, const int* in_sizes, int n_in,
                              void* d_out, int out_size, void* d_ws, size_t ws_size,
                              hipStream_t stream) {
    const float* x     = (const float*)d_in[0];
    const int*   ei    = (const int*)d_in[1];
    const float* W1    = (const float*)d_in[2];
    const float* b1    = (const float*)d_in[3];
    const float* gamma = (const float*)d_in[4];
    const float* beta  = (const float*)d_in[5];
    const float* W2    = (const float*)d_in[6];
    const float* b2    = (const float*)d_in[7];
    const int* row = ei;          // edge_index[0]
    const int* col = ei + NE;     // edge_index[1]
    float* out = (float*)d_out;

    char* wp = (char*)d_ws;
    auto alloc = [&](size_t bytes) -> void* {
        void* p = (void*)wp;
        wp += (bytes + 255) & ~(size_t)255;
        return p;
    };
    unsigned short* h1b = (unsigned short*)alloc((size_t)NN * HID * 2);
    unsigned* aggb = (unsigned*)alloc((size_t)NN * HID * 2);
    unsigned short* h2b = (unsigned short*)alloc((size_t)NN * OUTC * 2);
    float* dinv    = (float*)alloc((size_t)NN * 4);
    float* bnsum   = (float*)alloc(HID * 4);
    float* bnsumsq = (float*)alloc(HID * 4);
    float* bnscale = (float*)alloc(HID * 4);
    float* bnshift = (float*)alloc(HID * 4);
    int*   rowptr  = (int*)alloc((size_t)(NN + 1) * 4);
    int*   cnt     = (int*)alloc((size_t)NN * 4);
    int*   bsum    = (int*)alloc(NSCB * 4);
    int*   bhist   = (int*)alloc((size_t)NBUK * NBLK * 4);
    int*   bsum2   = (int*)alloc(NSCB * 4);
    int2*  ebuk    = (int2*)alloc((size_t)NE * 8);
    int2*  csr     = (int2*)alloc((size_t)NE * 8);
    unsigned short* W1T = (unsigned short*)alloc((size_t)HID * INC * 2);

    hipLaunchKernelGGL(k_init,   dim3(1), dim3(128), 0, stream, bnsum, bnsumsq);
    hipLaunchKernelGGL(k_bhist,  dim3(NBLK), dim3(256), 0, stream, col, bhist);
    hipLaunchKernelGGL(k_gscanA, dim3(NSCB), dim3(GS_B), 0, stream, bhist, bhist, bsum2, NBUK * NBLK);
    hipLaunchKernelGGL(k_gscanB, dim3(1), dim3(128), 0, stream, bsum2, NSCB);
    hipLaunchKernelGGL(k_bpart,  dim3(NBLK), dim3(256), 0, stream, row, col, bhist, bsum2, ebuk);
    hipLaunchKernelGGL(k_ncount, dim3(NBUK), dim3(256), 0, stream, ebuk, bhist, bsum2, cnt);
    hipLaunchKernelGGL(k_gscanA, dim3(NSCB), dim3(GS_B), 0, stream, cnt, rowptr, bsum, NN);
    hipLaunchKernelGGL(k_gscanB, dim3(1), dim3(128), 0, stream, bsum, NSCB);
    hipLaunchKernelGGL(k_scanC2, dim3(NSCB), dim3(GS_B), 0, stream, cnt, rowptr, dinv, bsum);
    hipLaunchKernelGGL(k_bfill,  dim3(NBUK), dim3(256), 0, stream, ebuk, bhist, bsum2, rowptr, dinv, csr);
    hipLaunchKernelGGL(k_prepW1, dim3(256), dim3(256), 0, stream, W1, W1T);
    hipLaunchKernelGGL(k_gemm1m, dim3((NN + 63) / 64), dim3(256), 0, stream, x, W1T, h1b);
    hipLaunchKernelGGL(k_agg1,   dim3(NN / 4), dim3(256), 0, stream, h1b, dinv, rowptr, csr, b1, aggb);
    hipLaunchKernelGGL(k_bnstats, dim3(256), dim3(256), 0, stream, aggb, bnsum, bnsumsq);
    hipLaunchKernelGGL(k_bnfinal, dim3(1), dim3(128), 0, stream, bnsum, bnsumsq, gamma, beta, bnscale, bnshift);
    hipLaunchKernelGGL(k_gemm2,  dim3((NN + 63) / 64), dim3(256), 0, stream, aggb, W2, bnscale, bnshift, h2b);
    hipLaunchKernelGGL(k_agg2,   dim3(NN / 4), dim3(256), 0, stream, h2b, dinv, rowptr, csr, b2, out);
}

// Round 6
// 325.589 us; speedup vs baseline: 1.4386x; 1.0654x over previous
//
#include <hip/hip_runtime.h>

#define NN 100000
#define NE 1600000
#define INC 512
#define HID 128
#define OUTC 64
#define BN_EPS 1e-5f

#define GS_B 1024
#define NSCB 98                   // scan blocks for NBUK*NBLK (=100096 <= 100352)

#define NBLK 256
#define CHUNK (NE / NBLK)         // 6250 exactly
#define BSH 8
#define NBUK ((NN + 255) >> 8)    // 391 buckets of 256 nodes

typedef __attribute__((ext_vector_type(8))) short short8v;
typedef __attribute__((ext_vector_type(4))) float f32x4;

__device__ __forceinline__ unsigned short f2bf(float f) {
    unsigned u = __float_as_uint(f);
    u += 0x7FFFu + ((u >> 16) & 1u);     // round-to-nearest-even
    return (unsigned short)(u >> 16);
}

// packed f32x2 -> bf16x2 (RNE), D[15:0]=bf16(lo), D[31:16]=bf16(hi)
__device__ __forceinline__ unsigned cvtpk(float lo, float hi) {
    unsigned r;
    asm("v_cvt_pk_bf16_f32 %0, %1, %2" : "=v"(r) : "v"(lo), "v"(hi));
    return r;
}

__device__ __forceinline__ float bflo(unsigned u) { return __uint_as_float(u << 16); }
__device__ __forceinline__ float bfhi(unsigned u) { return __uint_as_float(u & 0xFFFF0000u); }

// ---------------- bucketed CSR build ----------------

// per-(bucket, chunk) histogram; block 0 also zeroes BN accumulators
__global__ __launch_bounds__(256) void k_bhist(const int* __restrict__ col, int* __restrict__ bhist,
                                               float* bnsum, float* bnsumsq) {
    __shared__ int lc[NBUK];
    int tid = threadIdx.x, blk = blockIdx.x;
    if (blk == 0 && tid < HID) { bnsum[tid] = 0.f; bnsumsq[tid] = 0.f; }
    for (int i = tid; i < NBUK; i += 256) lc[i] = 0;
    __syncthreads();
    int s = blk * CHUNK, e = s + CHUNK;
    for (int j = s + tid; j < e; j += 256)
        atomicAdd(&lc[col[j] >> BSH], 1);
    __syncthreads();
    for (int i = tid; i < NBUK; i += 256)
        bhist[i * NBLK + blk] = lc[i];
}

// generic scan: per-block exclusive prefix (in-place safe) + block totals
__global__ void k_gscanA(const int* __restrict__ src, int* __restrict__ dst,
                         int* __restrict__ bsum, int n) {
    __shared__ int s[GS_B];
    int tid = threadIdx.x;
    int i = blockIdx.x * GS_B + tid;
    int v = (i < n) ? src[i] : 0;
    s[tid] = v;
    __syncthreads();
    for (int off = 1; off < GS_B; off <<= 1) {
        int t = (tid >= off) ? s[tid - off] : 0;
        __syncthreads();
        s[tid] += t;
        __syncthreads();
    }
    if (i < n) dst[i] = s[tid] - v;
    if (tid == GS_B - 1) bsum[blockIdx.x] = s[tid];
}

__global__ void k_gscanB(int* bsum, int nb) {
    __shared__ int s[256];
    int tid = threadIdx.x;
    for (int i = tid; i < nb; i += blockDim.x) s[i] = bsum[i];
    __syncthreads();
    if (tid == 0) {
        int run = 0;
        for (int i = 0; i < nb; ++i) { int t = s[i]; s[i] = run; run += t; }
    }
    __syncthreads();
    for (int i = tid; i < nb; i += blockDim.x) bsum[i] = s[i];
}

// partition edges into buckets; entry = row | (local_col << 24)
__global__ __launch_bounds__(256) void k_bpart(const int* __restrict__ row, const int* __restrict__ col,
                                               const int* __restrict__ sb, const int* __restrict__ sbsum,
                                               unsigned* __restrict__ ebuk) {
    __shared__ int lcur[NBUK];
    int tid = threadIdx.x, blk = blockIdx.x;
    for (int i = tid; i < NBUK; i += 256) {
        int idx = i * NBLK + blk;
        lcur[i] = sb[idx] + sbsum[idx >> 10];
    }
    __syncthreads();
    int s = blk * CHUNK, e = s + CHUNK;
    for (int j = s + tid; j < e; j += 256) {
        int r = row[j], c = col[j];
        int p = atomicAdd(&lcur[c >> BSH], 1);
        ebuk[p] = (unsigned)r | ((unsigned)(c & 255) << 24);
    }
}

// per-bucket: node counts -> deg[], local exclusive scan -> rowptr[]
__global__ __launch_bounds__(256) void k_nprep(const unsigned* __restrict__ ebuk,
                                               const int* __restrict__ sb, const int* __restrict__ sbsum,
                                               int* __restrict__ deg, int* __restrict__ rowptr) {
    __shared__ int lc[256];
    __shared__ int sc[256];
    int b = blockIdx.x, tid = threadIdx.x;
    lc[tid] = 0;
    __syncthreads();
    int i0 = b * NBLK;
    int s = sb[i0] + sbsum[i0 >> 10];
    int e2 = (b + 1 < NBUK) ? (sb[i0 + NBLK] + sbsum[(i0 + NBLK) >> 10]) : NE;
    for (int j = s + tid; j < e2; j += 256)
        atomicAdd(&lc[ebuk[j] >> 24], 1);
    __syncthreads();
    int v = lc[tid];
    sc[tid] = v;
    __syncthreads();
    for (int off = 1; off < 256; off <<= 1) {
        int t = (tid >= off) ? sc[tid - off] : 0;
        __syncthreads();
        sc[tid] += t;
        __syncthreads();
    }
    int node = (b << BSH) + tid;
    if (node < NN) {
        deg[node] = v;
        rowptr[node] = s + sc[tid] - v;
    }
    if (b == NBUK - 1 && tid == 0) rowptr[NN] = NE;
}

// scatter csr entries: entry = row | (deg[row] << 17)
__global__ __launch_bounds__(256) void k_bfill(const unsigned* __restrict__ ebuk,
                                               const int* __restrict__ sb, const int* __restrict__ sbsum,
                                               const int* __restrict__ rowptr, const int* __restrict__ deg,
                                               unsigned* __restrict__ csr) {
    __shared__ int lcur[256];
    int b = blockIdx.x, tid = threadIdx.x;
    int node0 = b << BSH;
    int node = node0 + tid;
    lcur[tid] = (node < NN) ? rowptr[node] : 0;
    __syncthreads();
    int i0 = b * NBLK;
    int s = sb[i0] + sbsum[i0 >> 10];
    int e2 = (b + 1 < NBUK) ? (sb[i0 + NBLK] + sbsum[(i0 + NBLK) >> 10]) : NE;
    for (int j = s + tid; j < e2; j += 256) {
        unsigned rc = ebuk[j];
        int li = rc >> 24;
        int r = rc & 0xFFFFFF;
        int p = atomicAdd(&lcur[li], 1);
        csr[p] = (unsigned)r | ((unsigned)deg[r] << 17);
    }
}

// ---------------- W1 -> bf16 transposed [128][512] ----------------

__global__ void k_prepW1(const float* __restrict__ W1, unsigned short* __restrict__ W1T) {
    int i = blockIdx.x * 256 + threadIdx.x;    // 65536 elements
    int k = i >> 7, n = i & 127;
    W1T[(size_t)n * INC + k] = f2bf(W1[i]);
}

// ---------------- GEMM1 (MFMA): h1b[N,128](bf16) = bf16(x)[N,512] @ bf16(W1)[512,128] ----------------
// register-prefetch double-stage: global loads for tile t+1 issued before MFMA of tile t.

#define G1BK 64
#define APAD 72   // LDS row stride in shorts (144B -> 2-way bank alias, free)

__global__ __launch_bounds__(256) void k_gemm1m(const float* __restrict__ x,
                                                const unsigned short* __restrict__ W1T,
                                                unsigned short* __restrict__ h1b) {
    __shared__ unsigned short As[64][APAD];
    __shared__ unsigned short Bs[128][APAD];
    int tid = threadIdx.x;
    int m0 = blockIdx.x * 64;
    int w = tid >> 6;
    int lane = tid & 63;

    f32x4 acc[4][2];
    #pragma unroll
    for (int mr = 0; mr < 4; ++mr)
        #pragma unroll
        for (int cb = 0; cb < 2; ++cb) acc[mr][cb] = (f32x4){0.f, 0.f, 0.f, 0.f};

    int ar = tid >> 2;
    int ak = (tid & 3) * 16;
    int arow = m0 + ar; if (arow >= NN) arow = NN - 1;
    const float* xr = x + (size_t)arow * INC;
    int br = tid >> 1;
    int bk = (tid & 1) * 32;
    const unsigned short* wr = W1T + (size_t)br * INC;

    int frow = lane & 15;
    int fk = (lane >> 4) * 8;

    float4 pv[4];
    short8v pb[4];
    #pragma unroll
    for (int q = 0; q < 4; ++q) pv[q] = *(const float4*)(xr + ak + q * 4);
    #pragma unroll
    for (int q = 0; q < 4; ++q) pb[q] = *(const short8v*)(wr + bk + q * 8);

    for (int k0 = 0; k0 < INC; k0 += G1BK) {
        #pragma unroll
        for (int q = 0; q < 4; ++q)
            *(uint2*)&As[ar][ak + q * 4] = make_uint2(cvtpk(pv[q].x, pv[q].y), cvtpk(pv[q].z, pv[q].w));
        #pragma unroll
        for (int q = 0; q < 4; ++q)
            *(short8v*)&Bs[br][bk + q * 8] = pb[q];
        __syncthreads();
        if (k0 + G1BK < INC) {
            #pragma unroll
            for (int q = 0; q < 4; ++q) pv[q] = *(const float4*)(xr + k0 + G1BK + ak + q * 4);
            #pragma unroll
            for (int q = 0; q < 4; ++q) pb[q] = *(const short8v*)(wr + k0 + G1BK + bk + q * 8);
        }
        #pragma unroll
        for (int kk = 0; kk < G1BK; kk += 32) {
            short8v a[4], b[2];
            #pragma unroll
            for (int mr = 0; mr < 4; ++mr)
                a[mr] = *(const short8v*)&As[16 * mr + frow][kk + fk];   // x nodes (B operand)
            #pragma unroll
            for (int cb = 0; cb < 2; ++cb)
                b[cb] = *(const short8v*)&Bs[32 * w + 16 * cb + frow][kk + fk];  // W channels (A operand)
            #pragma unroll
            for (int mr = 0; mr < 4; ++mr)
                #pragma unroll
                for (int cb = 0; cb < 2; ++cb)
                    acc[mr][cb] = __builtin_amdgcn_mfma_f32_16x16x32_bf16(b[cb], a[mr], acc[mr][cb], 0, 0, 0);
        }
        __syncthreads();
    }
    int ncol = lane & 15;
    int r4 = (lane >> 4) * 4;
    #pragma unroll
    for (int mr = 0; mr < 4; ++mr) {
        int node = m0 + 16 * mr + ncol;
        if (node < NN) {
            #pragma unroll
            for (int cb = 0; cb < 2; ++cb) {
                int ch = 32 * w + 16 * cb + r4;
                *(uint2*)&h1b[(size_t)node * HID + ch] =
                    make_uint2(cvtpk(acc[mr][cb][0], acc[mr][cb][1]),
                               cvtpk(acc[mr][cb][2], acc[mr][cb][3]));
            }
        }
    }
}

// ---------------- aggregation 1 (128 ch bf16 -> bf16): 1 wave/node, in-entry degree ----------------

__global__ __launch_bounds__(256) void k_agg1(const unsigned short* __restrict__ h1b,
                                              const int* __restrict__ deg,
                                              const int* __restrict__ rowptr, const unsigned* __restrict__ csr,
                                              const float* __restrict__ b1, unsigned* __restrict__ aggb) {
    int node = blockIdx.x * 4 + (threadIdx.x >> 6);
    int lane = threadIdx.x & 63;
    const unsigned* hp = (const unsigned*)h1b;     // 64 uints per row (2 bf16 ch each)
    size_t base = (size_t)node * 64 + lane;
    float dnf = (float)(deg[node] + 1);
    float di = rsqrtf(dnf);
    float wself = di * di;
    unsigned hv = hp[base];
    float sx = wself * bflo(hv);
    float sy = wself * bfhi(hv);
    int s = rowptr[node], e = rowptr[node + 1];
    int j = s;
    for (; j + 4 <= e; j += 4) {
        unsigned c0 = csr[j], c1 = csr[j + 1], c2 = csr[j + 2], c3 = csr[j + 3];
        int r0 = c0 & 0x1FFFF, r1 = c1 & 0x1FFFF, r2 = c2 & 0x1FFFF, r3 = c3 & 0x1FFFF;
        unsigned v0 = hp[(size_t)r0 * 64 + lane];
        unsigned v1 = hp[(size_t)r1 * 64 + lane];
        unsigned v2 = hp[(size_t)r2 * 64 + lane];
        unsigned v3 = hp[(size_t)r3 * 64 + lane];
        float w0 = rsqrtf(dnf * (float)((c0 >> 17) + 1));
        float w1 = rsqrtf(dnf * (float)((c1 >> 17) + 1));
        float w2 = rsqrtf(dnf * (float)((c2 >> 17) + 1));
        float w3 = rsqrtf(dnf * (float)((c3 >> 17) + 1));
        sx = fmaf(w0, bflo(v0), sx); sy = fmaf(w0, bfhi(v0), sy);
        sx = fmaf(w1, bflo(v1), sx); sy = fmaf(w1, bfhi(v1), sy);
        sx = fmaf(w2, bflo(v2), sx); sy = fmaf(w2, bfhi(v2), sy);
        sx = fmaf(w3, bflo(v3), sx); sy = fmaf(w3, bfhi(v3), sy);
    }
    for (; j < e; ++j) {
        unsigned c = csr[j];
        int r = c & 0x1FFFF;
        unsigned v = hp[(size_t)r * 64 + lane];
        float ww = rsqrtf(dnf * (float)((c >> 17) + 1));
        sx = fmaf(ww, bflo(v), sx); sy = fmaf(ww, bfhi(v), sy);
    }
    float2 bb = ((const float2*)b1)[lane];
    aggb[base] = cvtpk(sx + bb.x, sy + bb.y);
}

// ---------------- BN stats (from bf16 agg) ----------------

__global__ __launch_bounds__(256) void k_bnstats(const unsigned* __restrict__ aggb,
                                                 float* __restrict__ bnsum, float* __restrict__ bnsumsq) {
    __shared__ float4 ss[256], sq[256];
    int g = threadIdx.x & 31;          // 4-channel group: channels 4g..4g+3
    int h = threadIdx.x >> 5;          // 0..7 row offset
    float4 fs = make_float4(0.f, 0.f, 0.f, 0.f);
    float4 fq = make_float4(0.f, 0.f, 0.f, 0.f);
    int rows_per_block = (NN + gridDim.x - 1) / gridDim.x;
    int r0 = blockIdx.x * rows_per_block;
    int r1 = r0 + rows_per_block; if (r1 > NN) r1 = NN;
    for (int r = r0 + h; r < r1; r += 8) {
        uint2 u = *(const uint2*)(aggb + (size_t)r * 64 + 2 * g);
        float a0 = bflo(u.x), a1 = bfhi(u.x), a2 = bflo(u.y), a3 = bfhi(u.y);
        fs.x += a0; fs.y += a1; fs.z += a2; fs.w += a3;
        fq.x += a0 * a0; fq.y += a1 * a1; fq.z += a2 * a2; fq.w += a3 * a3;
    }
    ss[threadIdx.x] = fs; sq[threadIdx.x] = fq;
    __syncthreads();
    if (threadIdx.x < 32) {
        float4 as = ss[threadIdx.x], aq = sq[threadIdx.x];
        #pragma unroll
        for (int k = 1; k < 8; ++k) {
            float4 bs = ss[k * 32 + threadIdx.x], bq = sq[k * 32 + threadIdx.x];
            as.x += bs.x; as.y += bs.y; as.z += bs.z; as.w += bs.w;
            aq.x += bq.x; aq.y += bq.y; aq.z += bq.z; aq.w += bq.w;
        }
        atomicAdd(&bnsum[4 * g + 0], as.x); atomicAdd(&bnsum[4 * g + 1], as.y);
        atomicAdd(&bnsum[4 * g + 2], as.z); atomicAdd(&bnsum[4 * g + 3], as.w);
        atomicAdd(&bnsumsq[4 * g + 0], aq.x); atomicAdd(&bnsumsq[4 * g + 1], aq.y);
        atomicAdd(&bnsumsq[4 * g + 2], aq.z); atomicAdd(&bnsumsq[4 * g + 3], aq.w);
    }
}

__global__ void k_bnfinal(const float* __restrict__ bnsum, const float* __restrict__ bnsumsq,
                          const float* __restrict__ gamma, const float* __restrict__ beta,
                          float* __restrict__ bnscale, float* __restrict__ bnshift) {
    int c = threadIdx.x;
    if (c < HID) {
        float mu = bnsum[c] / (float)NN;
        float var = bnsumsq[c] / (float)NN - mu * mu;
        float sc = gamma[c] * rsqrtf(var + BN_EPS);
        bnscale[c] = sc;
        bnshift[c] = beta[c] - mu * sc;
    }
}

// ---------------- GEMM2: h2b[N,64](bf16) = relu(bn(aggb)) @ W2[128,64], BN+ReLU fused ----------------

__global__ __launch_bounds__(256) void k_gemm2(const unsigned* __restrict__ aggb, const float* __restrict__ W2,
                                               const float* __restrict__ bnscale, const float* __restrict__ bnshift,
                                               unsigned short* __restrict__ h2b) {
    __shared__ float As2[32][66];
    __shared__ float Bs2[32][OUTC];
    int tid = threadIdx.x;
    int m0 = blockIdx.x * 64;
    int tx = tid & 15, ty = tid >> 4;
    float acc[4][4];
    #pragma unroll
    for (int r = 0; r < 4; ++r)
        #pragma unroll
        for (int c = 0; c < 4; ++c) acc[r][c] = 0.f;

    int am = tid >> 3;          // 0..31
    int ak = (tid & 7) * 4;     // 0..28
    int bk = tid >> 4;          // 0..15
    int bc = (tid & 15) * 4;    // 0..60

    for (int k0 = 0; k0 < HID; k0 += 32) {
        #pragma unroll
        for (int h = 0; h < 2; ++h) {
            int m = am + h * 32;
            int rowi = m0 + m; if (rowi >= NN) rowi = NN - 1;
            uint2 u = *(const uint2*)(aggb + (size_t)rowi * 64 + ((k0 + ak) >> 1));
            float4 sc = *(const float4*)(bnscale + k0 + ak);
            float4 sh = *(const float4*)(bnshift + k0 + ak);
            As2[ak + 0][m] = fmaxf(fmaf(bflo(u.x), sc.x, sh.x), 0.f);
            As2[ak + 1][m] = fmaxf(fmaf(bfhi(u.x), sc.y, sh.y), 0.f);
            As2[ak + 2][m] = fmaxf(fmaf(bflo(u.y), sc.z, sh.z), 0.f);
            As2[ak + 3][m] = fmaxf(fmaf(bfhi(u.y), sc.w, sh.w), 0.f);
        }
        #pragma unroll
        for (int h = 0; h < 2; ++h) {
            int k = bk + h * 16;
            *(float4*)&Bs2[k][bc] = *(const float4*)(W2 + (size_t)(k0 + k) * OUTC + bc);
        }
        __syncthreads();
        #pragma unroll
        for (int k = 0; k < 32; ++k) {
            float a[4];
            #pragma unroll
            for (int r = 0; r < 4; ++r) a[r] = As2[k][ty * 4 + r];
            float4 b = *(const float4*)&Bs2[k][tx * 4];
            #pragma unroll
            for (int r = 0; r < 4; ++r) {
                acc[r][0] = fmaf(a[r], b.x, acc[r][0]);
                acc[r][1] = fmaf(a[r], b.y, acc[r][1]);
                acc[r][2] = fmaf(a[r], b.z, acc[r][2]);
                acc[r][3] = fmaf(a[r], b.w, acc[r][3]);
            }
        }
        __syncthreads();
    }
    #pragma unroll
    for (int r = 0; r < 4; ++r) {
        int m = m0 + ty * 4 + r;
        if (m < NN) {
            *(uint2*)(h2b + (size_t)m * OUTC + tx * 4) =
                make_uint2(cvtpk(acc[r][0], acc[r][1]), cvtpk(acc[r][2], acc[r][3]));
        }
    }
}

// ---------------- aggregation 2 (64 ch bf16): 1 wave/node, lane-halves alternate edges ----------------

__global__ __launch_bounds__(256) void k_agg2(const unsigned short* __restrict__ h2b,
                                              const int* __restrict__ deg,
                                              const int* __restrict__ rowptr, const unsigned* __restrict__ csr,
                                              const float* __restrict__ b2, float* __restrict__ out) {
    int node = blockIdx.x * 4 + (threadIdx.x >> 6);
    int lane = threadIdx.x & 63;
    int l32 = lane & 31;
    const unsigned* hp = (const unsigned*)h2b;     // 32 uints per row (2 bf16 ch each)
    float dnf = (float)(deg[node] + 1);
    float di = rsqrtf(dnf);
    float wself = di * di;
    float sx = 0.f, sy = 0.f;
    if (lane < 32) {
        unsigned u = hp[(size_t)node * 32 + l32];
        sx = wself * bflo(u);
        sy = wself * bfhi(u);
    }
    int s = rowptr[node], e = rowptr[node + 1];
    int j = s + (lane >> 5);
    for (; j + 2 < e; j += 4) {
        unsigned c0 = csr[j], c1 = csr[j + 2];
        int r0 = c0 & 0x1FFFF, r1 = c1 & 0x1FFFF;
        unsigned v0 = hp[(size_t)r0 * 32 + l32];
        unsigned v1 = hp[(size_t)r1 * 32 + l32];
        float w0 = rsqrtf(dnf * (float)((c0 >> 17) + 1));
        float w1 = rsqrtf(dnf * (float)((c1 >> 17) + 1));
        sx = fmaf(w0, bflo(v0), sx); sy = fmaf(w0, bfhi(v0), sy);
        sx = fmaf(w1, bflo(v1), sx); sy = fmaf(w1, bfhi(v1), sy);
    }
    if (j < e) {
        unsigned c = csr[j];
        int r = c & 0x1FFFF;
        unsigned v = hp[(size_t)r * 32 + l32];
        float ww = rsqrtf(dnf * (float)((c >> 17) + 1));
        sx = fmaf(ww, bflo(v), sx); sy = fmaf(ww, bfhi(v), sy);
    }
    sx += __shfl_xor(sx, 32);
    sy += __shfl_xor(sy, 32);
    if (lane < 32) {
        float2 bb = ((const float2*)b2)[l32];
        ((float2*)out)[(size_t)node * 32 + l32] = make_float2(sx + bb.x, sy + bb.y);
    }
}

// ---------------- launch ----------------

extern "C" void kernel_launch(void* const* d_in, const int* in_sizes, int n_in,
                              void* d_out, int out_size, void* d_ws, size_t ws_size,
                              hipStream_t stream) {
    const float* x     = (const float*)d_in[0];
    const int*   ei    = (const int*)d_in[1];
    const float* W1    = (const float*)d_in[2];
    const float* b1    = (const float*)d_in[3];
    const float* gamma = (const float*)d_in[4];
    const float* beta  = (const float*)d_in[5];
    const float* W2    = (const float*)d_in[6];
    const float* b2    = (const float*)d_in[7];
    const int* row = ei;          // edge_index[0]
    const int* col = ei + NE;     // edge_index[1]
    float* out = (float*)d_out;

    char* wp = (char*)d_ws;
    auto alloc = [&](size_t bytes) -> void* {
        void* p = (void*)wp;
        wp += (bytes + 255) & ~(size_t)255;
        return p;
    };
    unsigned short* h1b = (unsigned short*)alloc((size_t)NN * HID * 2);
    unsigned* aggb = (unsigned*)alloc((size_t)NN * HID * 2);
    unsigned short* h2b = (unsigned short*)alloc((size_t)NN * OUTC * 2);
    int*   deg     = (int*)alloc((size_t)NN * 4);
    float* bnsum   = (float*)alloc(HID * 4);
    float* bnsumsq = (float*)alloc(HID * 4);
    float* bnscale = (float*)alloc(HID * 4);
    float* bnshift = (float*)alloc(HID * 4);
    int*   rowptr  = (int*)alloc((size_t)(NN + 1) * 4);
    int*   bhist   = (int*)alloc((size_t)NBUK * NBLK * 4);
    int*   bsum2   = (int*)alloc(NSCB * 4);
    unsigned* ebuk = (unsigned*)alloc((size_t)NE * 4);
    unsigned* csr  = (unsigned*)alloc((size_t)NE * 4);
    unsigned short* W1T = (unsigned short*)alloc((size_t)HID * INC * 2);

    hipLaunchKernelGGL(k_bhist,  dim3(NBLK), dim3(256), 0, stream, col, bhist, bnsum, bnsumsq);
    hipLaunchKernelGGL(k_gscanA, dim3(NSCB), dim3(GS_B), 0, stream, bhist, bhist, bsum2, NBUK * NBLK);
    hipLaunchKernelGGL(k_gscanB, dim3(1), dim3(128), 0, stream, bsum2, NSCB);
    hipLaunchKernelGGL(k_bpart,  dim3(NBLK), dim3(256), 0, stream, row, col, bhist, bsum2, ebuk);
    hipLaunchKernelGGL(k_nprep,  dim3(NBUK), dim3(256), 0, stream, ebuk, bhist, bsum2, deg, rowptr);
    hipLaunchKernelGGL(k_bfill,  dim3(NBUK), dim3(256), 0, stream, ebuk, bhist, bsum2, rowptr, deg, csr);
    hipLaunchKernelGGL(k_prepW1, dim3(256), dim3(256), 0, stream, W1, W1T);
    hipLaunchKernelGGL(k_gemm1m, dim3((NN + 63) / 64), dim3(256), 0, stream, x, W1T, h1b);
    hipLaunchKernelGGL(k_agg1,   dim3(NN / 4), dim3(256), 0, stream, h1b, deg, rowptr, csr, b1, aggb);
    hipLaunchKernelGGL(k_bnstats, dim3(256), dim3(256), 0, stream, aggb, bnsum, bnsumsq);
    hipLaunchKernelGGL(k_bnfinal, dim3(1), dim3(128), 0, stream, bnsum, bnsumsq, gamma, beta, bnscale, bnshift);
    hipLaunchKernelGGL(k_gemm2,  dim3((NN + 63) / 64), dim3(256), 0, stream, aggb, W2, bnscale, bnshift, h2b);
    hipLaunchKernelGGL(k_agg2,   dim3(NN / 4), dim3(256), 0, stream, h2b, deg, rowptr, csr, b2, out);
}

// Round 7
// 313.016 us; speedup vs baseline: 1.4964x; 1.0402x over previous
//
#include <hip/hip_runtime.h>

#define NN 100000
#define NE 1600000
#define INC 512
#define HID 128
#define OUTC 64
#define BN_EPS 1e-5f

#define GS_B 1024
#define NSCB 98                   // scan blocks for NBUK*NBLK (=100096 <= 100352)

#define NBLK 256
#define CHUNK (NE / NBLK)         // 6250 exactly
#define BSH 8
#define NBUK ((NN + 255) >> 8)    // 391 buckets of 256 nodes

typedef __attribute__((ext_vector_type(8))) short short8v;
typedef __attribute__((ext_vector_type(4))) float f32x4;

__device__ __forceinline__ unsigned short f2bf(float f) {
    unsigned u = __float_as_uint(f);
    u += 0x7FFFu + ((u >> 16) & 1u);     // round-to-nearest-even
    return (unsigned short)(u >> 16);
}

// packed f32x2 -> bf16x2 (RNE), D[15:0]=bf16(lo), D[31:16]=bf16(hi)
__device__ __forceinline__ unsigned cvtpk(float lo, float hi) {
    unsigned r;
    asm("v_cvt_pk_bf16_f32 %0, %1, %2" : "=v"(r) : "v"(lo), "v"(hi));
    return r;
}

__device__ __forceinline__ float bflo(unsigned u) { return __uint_as_float(u << 16); }
__device__ __forceinline__ float bfhi(unsigned u) { return __uint_as_float(u & 0xFFFF0000u); }

// scan the 98 raw block totals into an exclusive prefix, in LDS (per-block redundant)
__device__ __forceinline__ void scan_bsum(const int* __restrict__ bsum2, int* spref) {
    int tid = threadIdx.x;
    if (tid < NSCB) spref[tid] = bsum2[tid];
    __syncthreads();
    if (tid == 0) {
        int run = 0;
        #pragma unroll 1
        for (int i = 0; i < NSCB; ++i) { int t = spref[i]; spref[i] = run; run += t; }
    }
    __syncthreads();
}

// ---------------- fused: W1->bf16T + bucket histogram + BN-acc zero ----------------

__global__ __launch_bounds__(256) void k_pre(const int* __restrict__ col, int* __restrict__ bhist,
                                             const float* __restrict__ W1, unsigned short* __restrict__ W1T,
                                             float* bnsum, float* bnsumsq) {
    __shared__ int lc[NBUK];
    int tid = threadIdx.x, blk = blockIdx.x;
    int i = blk * 256 + tid;                     // 65536 W1 elements, grid is exactly 256 blocks
    W1T[(size_t)(i & 127) * INC + (i >> 7)] = f2bf(W1[i]);
    if (blk == 0 && tid < HID) { bnsum[tid] = 0.f; bnsumsq[tid] = 0.f; }
    for (int q = tid; q < NBUK; q += 256) lc[q] = 0;
    __syncthreads();
    int s = blk * CHUNK, e = s + CHUNK;
    for (int j = s + tid; j < e; j += 256)
        atomicAdd(&lc[col[j] >> BSH], 1);
    __syncthreads();
    for (int q = tid; q < NBUK; q += 256)
        bhist[q * NBLK + blk] = lc[q];
}

// generic scan: per-block exclusive prefix (in-place safe) + raw block totals
__global__ void k_gscanA(const int* __restrict__ src, int* __restrict__ dst,
                         int* __restrict__ bsum, int n) {
    __shared__ int s[GS_B];
    int tid = threadIdx.x;
    int i = blockIdx.x * GS_B + tid;
    int v = (i < n) ? src[i] : 0;
    s[tid] = v;
    __syncthreads();
    for (int off = 1; off < GS_B; off <<= 1) {
        int t = (tid >= off) ? s[tid - off] : 0;
        __syncthreads();
        s[tid] += t;
        __syncthreads();
    }
    if (i < n) dst[i] = s[tid] - v;
    if (tid == GS_B - 1) bsum[blockIdx.x] = s[tid];
}

// partition edges into buckets; entry = row | (local_col << 24)
__global__ __launch_bounds__(256) void k_bpart(const int* __restrict__ row, const int* __restrict__ col,
                                               const int* __restrict__ sb, const int* __restrict__ bsum2,
                                               unsigned* __restrict__ ebuk) {
    __shared__ int lcur[NBUK];
    __shared__ int spref[NSCB];
    int tid = threadIdx.x, blk = blockIdx.x;
    scan_bsum(bsum2, spref);
    for (int i = tid; i < NBUK; i += 256) {
        int idx = i * NBLK + blk;
        lcur[i] = sb[idx] + spref[idx >> 10];
    }
    __syncthreads();
    int s = blk * CHUNK, e = s + CHUNK;
    for (int j = s + tid; j < e; j += 256) {
        int r = row[j], c = col[j];
        int p = atomicAdd(&lcur[c >> BSH], 1);
        ebuk[p] = (unsigned)r | ((unsigned)(c & 255) << 24);
    }
}

// per-bucket: node counts -> deg[], local exclusive scan -> rowptr[]
__global__ __launch_bounds__(256) void k_nprep(const unsigned* __restrict__ ebuk,
                                               const int* __restrict__ sb, const int* __restrict__ bsum2,
                                               int* __restrict__ deg, int* __restrict__ rowptr) {
    __shared__ int lc[256];
    __shared__ int sc[256];
    __shared__ int spref[NSCB];
    int b = blockIdx.x, tid = threadIdx.x;
    scan_bsum(bsum2, spref);
    lc[tid] = 0;
    __syncthreads();
    int i0 = b * NBLK;
    int s = sb[i0] + spref[i0 >> 10];
    int e2 = (b + 1 < NBUK) ? (sb[i0 + NBLK] + spref[(i0 + NBLK) >> 10]) : NE;
    for (int j = s + tid; j < e2; j += 256)
        atomicAdd(&lc[ebuk[j] >> 24], 1);
    __syncthreads();
    int v = lc[tid];
    sc[tid] = v;
    __syncthreads();
    for (int off = 1; off < 256; off <<= 1) {
        int t = (tid >= off) ? sc[tid - off] : 0;
        __syncthreads();
        sc[tid] += t;
        __syncthreads();
    }
    int node = (b << BSH) + tid;
    if (node < NN) {
        deg[node] = v;
        rowptr[node] = s + sc[tid] - v;
    }
    if (b == NBUK - 1 && tid == 0) rowptr[NN] = NE;
}

// scatter csr entries: entry = row | (deg[row] << 17)
__global__ __launch_bounds__(256) void k_bfill(const unsigned* __restrict__ ebuk,
                                               const int* __restrict__ sb, const int* __restrict__ bsum2,
                                               const int* __restrict__ rowptr, const int* __restrict__ deg,
                                               unsigned* __restrict__ csr) {
    __shared__ int lcur[256];
    __shared__ int spref[NSCB];
    int b = blockIdx.x, tid = threadIdx.x;
    scan_bsum(bsum2, spref);
    int node0 = b << BSH;
    int node = node0 + tid;
    lcur[tid] = (node < NN) ? rowptr[node] : 0;
    __syncthreads();
    int i0 = b * NBLK;
    int s = sb[i0] + spref[i0 >> 10];
    int e2 = (b + 1 < NBUK) ? (sb[i0 + NBLK] + spref[(i0 + NBLK) >> 10]) : NE;
    for (int j = s + tid; j < e2; j += 256) {
        unsigned rc = ebuk[j];
        int li = rc >> 24;
        int r = rc & 0xFFFFFF;
        int p = atomicAdd(&lcur[li], 1);
        csr[p] = (unsigned)r | ((unsigned)deg[r] << 17);
    }
}

// ---------------- GEMM1 (MFMA): h1b[N,128](bf16) = bf16(x)[N,512] @ bf16(W1)[512,128] ----------------
// register-prefetch double-stage: global loads for tile t+1 issued before MFMA of tile t.

#define G1BK 64
#define APAD 72   // LDS row stride in shorts (144B -> 2-way bank alias, free)

__global__ __launch_bounds__(256) void k_gemm1m(const float* __restrict__ x,
                                                const unsigned short* __restrict__ W1T,
                                                unsigned short* __restrict__ h1b) {
    __shared__ unsigned short As[64][APAD];
    __shared__ unsigned short Bs[128][APAD];
    int tid = threadIdx.x;
    int m0 = blockIdx.x * 64;
    int w = tid >> 6;
    int lane = tid & 63;

    f32x4 acc[4][2];
    #pragma unroll
    for (int mr = 0; mr < 4; ++mr)
        #pragma unroll
        for (int cb = 0; cb < 2; ++cb) acc[mr][cb] = (f32x4){0.f, 0.f, 0.f, 0.f};

    int ar = tid >> 2;
    int ak = (tid & 3) * 16;
    int arow = m0 + ar; if (arow >= NN) arow = NN - 1;
    const float* xr = x + (size_t)arow * INC;
    int br = tid >> 1;
    int bk = (tid & 1) * 32;
    const unsigned short* wr = W1T + (size_t)br * INC;

    int frow = lane & 15;
    int fk = (lane >> 4) * 8;

    float4 pv[4];
    short8v pb[4];
    #pragma unroll
    for (int q = 0; q < 4; ++q) pv[q] = *(const float4*)(xr + ak + q * 4);
    #pragma unroll
    for (int q = 0; q < 4; ++q) pb[q] = *(const short8v*)(wr + bk + q * 8);

    for (int k0 = 0; k0 < INC; k0 += G1BK) {
        #pragma unroll
        for (int q = 0; q < 4; ++q)
            *(uint2*)&As[ar][ak + q * 4] = make_uint2(cvtpk(pv[q].x, pv[q].y), cvtpk(pv[q].z, pv[q].w));
        #pragma unroll
        for (int q = 0; q < 4; ++q)
            *(short8v*)&Bs[br][bk + q * 8] = pb[q];
        __syncthreads();
        if (k0 + G1BK < INC) {
            #pragma unroll
            for (int q = 0; q < 4; ++q) pv[q] = *(const float4*)(xr + k0 + G1BK + ak + q * 4);
            #pragma unroll
            for (int q = 0; q < 4; ++q) pb[q] = *(const short8v*)(wr + k0 + G1BK + bk + q * 8);
        }
        #pragma unroll
        for (int kk = 0; kk < G1BK; kk += 32) {
            short8v a[4], b[2];
            #pragma unroll
            for (int mr = 0; mr < 4; ++mr)
                a[mr] = *(const short8v*)&As[16 * mr + frow][kk + fk];   // x nodes (B operand)
            #pragma unroll
            for (int cb = 0; cb < 2; ++cb)
                b[cb] = *(const short8v*)&Bs[32 * w + 16 * cb + frow][kk + fk];  // W channels (A operand)
            #pragma unroll
            for (int mr = 0; mr < 4; ++mr)
                #pragma unroll
                for (int cb = 0; cb < 2; ++cb)
                    acc[mr][cb] = __builtin_amdgcn_mfma_f32_16x16x32_bf16(b[cb], a[mr], acc[mr][cb], 0, 0, 0);
        }
        __syncthreads();
    }
    int ncol = lane & 15;
    int r4 = (lane >> 4) * 4;
    #pragma unroll
    for (int mr = 0; mr < 4; ++mr) {
        int node = m0 + 16 * mr + ncol;
        if (node < NN) {
            #pragma unroll
            for (int cb = 0; cb < 2; ++cb) {
                int ch = 32 * w + 16 * cb + r4;
                *(uint2*)&h1b[(size_t)node * HID + ch] =
                    make_uint2(cvtpk(acc[mr][cb][0], acc[mr][cb][1]),
                               cvtpk(acc[mr][cb][2], acc[mr][cb][3]));
            }
        }
    }
}

// ---------------- aggregation 1 (128 ch bf16 -> bf16): 1 wave/node, 8-deep unroll ----------------

__global__ __launch_bounds__(256) void k_agg1(const unsigned short* __restrict__ h1b,
                                              const int* __restrict__ deg,
                                              const int* __restrict__ rowptr, const unsigned* __restrict__ csr,
                                              const float* __restrict__ b1, unsigned* __restrict__ aggb) {
    int node = blockIdx.x * 4 + (threadIdx.x >> 6);
    int lane = threadIdx.x & 63;
    const unsigned* hp = (const unsigned*)h1b;     // 64 uints per row (2 bf16 ch each)
    size_t base = (size_t)node * 64 + lane;
    float dnf = (float)(deg[node] + 1);
    float di = rsqrtf(dnf);
    float wself = di * di;
    unsigned hv = hp[base];
    float sx = wself * bflo(hv);
    float sy = wself * bfhi(hv);
    int s = rowptr[node], e = rowptr[node + 1];
    int j = s;
    for (; j + 8 <= e; j += 8) {
        unsigned c0 = csr[j],     c1 = csr[j + 1], c2 = csr[j + 2], c3 = csr[j + 3];
        unsigned c4 = csr[j + 4], c5 = csr[j + 5], c6 = csr[j + 6], c7 = csr[j + 7];
        unsigned v0 = hp[(size_t)(c0 & 0x1FFFF) * 64 + lane];
        unsigned v1 = hp[(size_t)(c1 & 0x1FFFF) * 64 + lane];
        unsigned v2 = hp[(size_t)(c2 & 0x1FFFF) * 64 + lane];
        unsigned v3 = hp[(size_t)(c3 & 0x1FFFF) * 64 + lane];
        unsigned v4 = hp[(size_t)(c4 & 0x1FFFF) * 64 + lane];
        unsigned v5 = hp[(size_t)(c5 & 0x1FFFF) * 64 + lane];
        unsigned v6 = hp[(size_t)(c6 & 0x1FFFF) * 64 + lane];
        unsigned v7 = hp[(size_t)(c7 & 0x1FFFF) * 64 + lane];
        float w0 = rsqrtf(dnf * (float)((c0 >> 17) + 1));
        float w1 = rsqrtf(dnf * (float)((c1 >> 17) + 1));
        float w2 = rsqrtf(dnf * (float)((c2 >> 17) + 1));
        float w3 = rsqrtf(dnf * (float)((c3 >> 17) + 1));
        float w4 = rsqrtf(dnf * (float)((c4 >> 17) + 1));
        float w5 = rsqrtf(dnf * (float)((c5 >> 17) + 1));
        float w6 = rsqrtf(dnf * (float)((c6 >> 17) + 1));
        float w7 = rsqrtf(dnf * (float)((c7 >> 17) + 1));
        sx = fmaf(w0, bflo(v0), sx); sy = fmaf(w0, bfhi(v0), sy);
        sx = fmaf(w1, bflo(v1), sx); sy = fmaf(w1, bfhi(v1), sy);
        sx = fmaf(w2, bflo(v2), sx); sy = fmaf(w2, bfhi(v2), sy);
        sx = fmaf(w3, bflo(v3), sx); sy = fmaf(w3, bfhi(v3), sy);
        sx = fmaf(w4, bflo(v4), sx); sy = fmaf(w4, bfhi(v4), sy);
        sx = fmaf(w5, bflo(v5), sx); sy = fmaf(w5, bfhi(v5), sy);
        sx = fmaf(w6, bflo(v6), sx); sy = fmaf(w6, bfhi(v6), sy);
        sx = fmaf(w7, bflo(v7), sx); sy = fmaf(w7, bfhi(v7), sy);
    }
    for (; j + 4 <= e; j += 4) {
        unsigned c0 = csr[j], c1 = csr[j + 1], c2 = csr[j + 2], c3 = csr[j + 3];
        unsigned v0 = hp[(size_t)(c0 & 0x1FFFF) * 64 + lane];
        unsigned v1 = hp[(size_t)(c1 & 0x1FFFF) * 64 + lane];
        unsigned v2 = hp[(size_t)(c2 & 0x1FFFF) * 64 + lane];
        unsigned v3 = hp[(size_t)(c3 & 0x1FFFF) * 64 + lane];
        float w0 = rsqrtf(dnf * (float)((c0 >> 17) + 1));
        float w1 = rsqrtf(dnf * (float)((c1 >> 17) + 1));
        float w2 = rsqrtf(dnf * (float)((c2 >> 17) + 1));
        float w3 = rsqrtf(dnf * (float)((c3 >> 17) + 1));
        sx = fmaf(w0, bflo(v0), sx); sy = fmaf(w0, bfhi(v0), sy);
        sx = fmaf(w1, bflo(v1), sx); sy = fmaf(w1, bfhi(v1), sy);
        sx = fmaf(w2, bflo(v2), sx); sy = fmaf(w2, bfhi(v2), sy);
        sx = fmaf(w3, bflo(v3), sx); sy = fmaf(w3, bfhi(v3), sy);
    }
    for (; j < e; ++j) {
        unsigned c = csr[j];
        unsigned v = hp[(size_t)(c & 0x1FFFF) * 64 + lane];
        float ww = rsqrtf(dnf * (float)((c >> 17) + 1));
        sx = fmaf(ww, bflo(v), sx); sy = fmaf(ww, bfhi(v), sy);
    }
    float2 bb = ((const float2*)b1)[lane];
    aggb[base] = cvtpk(sx + bb.x, sy + bb.y);
}

// ---------------- BN stats (from bf16 agg) ----------------

__global__ __launch_bounds__(256) void k_bnstats(const unsigned* __restrict__ aggb,
                                                 float* __restrict__ bnsum, float* __restrict__ bnsumsq) {
    __shared__ float4 ss[256], sq[256];
    int g = threadIdx.x & 31;          // 4-channel group: channels 4g..4g+3
    int h = threadIdx.x >> 5;          // 0..7 row offset
    float4 fs = make_float4(0.f, 0.f, 0.f, 0.f);
    float4 fq = make_float4(0.f, 0.f, 0.f, 0.f);
    int rows_per_block = (NN + gridDim.x - 1) / gridDim.x;
    int r0 = blockIdx.x * rows_per_block;
    int r1 = r0 + rows_per_block; if (r1 > NN) r1 = NN;
    for (int r = r0 + h; r < r1; r += 8) {
        uint2 u = *(const uint2*)(aggb + (size_t)r * 64 + 2 * g);
        float a0 = bflo(u.x), a1 = bfhi(u.x), a2 = bflo(u.y), a3 = bfhi(u.y);
        fs.x += a0; fs.y += a1; fs.z += a2; fs.w += a3;
        fq.x += a0 * a0; fq.y += a1 * a1; fq.z += a2 * a2; fq.w += a3 * a3;
    }
    ss[threadIdx.x] = fs; sq[threadIdx.x] = fq;
    __syncthreads();
    if (threadIdx.x < 32) {
        float4 as = ss[threadIdx.x], aq = sq[threadIdx.x];
        #pragma unroll
        for (int k = 1; k < 8; ++k) {
            float4 bs = ss[k * 32 + threadIdx.x], bq = sq[k * 32 + threadIdx.x];
            as.x += bs.x; as.y += bs.y; as.z += bs.z; as.w += bs.w;
            aq.x += bq.x; aq.y += bq.y; aq.z += bq.z; aq.w += bq.w;
        }
        atomicAdd(&bnsum[4 * g + 0], as.x); atomicAdd(&bnsum[4 * g + 1], as.y);
        atomicAdd(&bnsum[4 * g + 2], as.z); atomicAdd(&bnsum[4 * g + 3], as.w);
        atomicAdd(&bnsumsq[4 * g + 0], aq.x); atomicAdd(&bnsumsq[4 * g + 1], aq.y);
        atomicAdd(&bnsumsq[4 * g + 2], aq.z); atomicAdd(&bnsumsq[4 * g + 3], aq.w);
    }
}

// ---------------- GEMM2 (+inline BN finalize): h2b = relu(bn(aggb)) @ W2 ----------------

__global__ __launch_bounds__(256) void k_gemm2(const unsigned* __restrict__ aggb, const float* __restrict__ W2,
                                               const float* __restrict__ bnsum, const float* __restrict__ bnsumsq,
                                               const float* __restrict__ gamma, const float* __restrict__ beta,
                                               unsigned short* __restrict__ h2b) {
    __shared__ float As2[32][66];
    __shared__ float Bs2[32][OUTC];
    __shared__ float bnsc[HID], bnsh[HID];
    int tid = threadIdx.x;
    if (tid < HID) {
        float mu = bnsum[tid] / (float)NN;
        float var = bnsumsq[tid] / (float)NN - mu * mu;
        float sc = gamma[tid] * rsqrtf(var + BN_EPS);
        bnsc[tid] = sc;
        bnsh[tid] = beta[tid] - mu * sc;
    }
    __syncthreads();
    int m0 = blockIdx.x * 64;
    int tx = tid & 15, ty = tid >> 4;
    float acc[4][4];
    #pragma unroll
    for (int r = 0; r < 4; ++r)
        #pragma unroll
        for (int c = 0; c < 4; ++c) acc[r][c] = 0.f;

    int am = tid >> 3;          // 0..31
    int ak = (tid & 7) * 4;     // 0..28
    int bk = tid >> 4;          // 0..15
    int bc = (tid & 15) * 4;    // 0..60

    for (int k0 = 0; k0 < HID; k0 += 32) {
        #pragma unroll
        for (int h = 0; h < 2; ++h) {
            int m = am + h * 32;
            int rowi = m0 + m; if (rowi >= NN) rowi = NN - 1;
            uint2 u = *(const uint2*)(aggb + (size_t)rowi * 64 + ((k0 + ak) >> 1));
            float4 sc = *(const float4*)&bnsc[k0 + ak];
            float4 sh = *(const float4*)&bnsh[k0 + ak];
            As2[ak + 0][m] = fmaxf(fmaf(bflo(u.x), sc.x, sh.x), 0.f);
            As2[ak + 1][m] = fmaxf(fmaf(bfhi(u.x), sc.y, sh.y), 0.f);
            As2[ak + 2][m] = fmaxf(fmaf(bflo(u.y), sc.z, sh.z), 0.f);
            As2[ak + 3][m] = fmaxf(fmaf(bfhi(u.y), sc.w, sh.w), 0.f);
        }
        #pragma unroll
        for (int h = 0; h < 2; ++h) {
            int k = bk + h * 16;
            *(float4*)&Bs2[k][bc] = *(const float4*)(W2 + (size_t)(k0 + k) * OUTC + bc);
        }
        __syncthreads();
        #pragma unroll
        for (int k = 0; k < 32; ++k) {
            float a[4];
            #pragma unroll
            for (int r = 0; r < 4; ++r) a[r] = As2[k][ty * 4 + r];
            float4 b = *(const float4*)&Bs2[k][tx * 4];
            #pragma unroll
            for (int r = 0; r < 4; ++r) {
                acc[r][0] = fmaf(a[r], b.x, acc[r][0]);
                acc[r][1] = fmaf(a[r], b.y, acc[r][1]);
                acc[r][2] = fmaf(a[r], b.z, acc[r][2]);
                acc[r][3] = fmaf(a[r], b.w, acc[r][3]);
            }
        }
        __syncthreads();
    }
    #pragma unroll
    for (int r = 0; r < 4; ++r) {
        int m = m0 + ty * 4 + r;
        if (m < NN) {
            *(uint2*)(h2b + (size_t)m * OUTC + tx * 4) =
                make_uint2(cvtpk(acc[r][0], acc[r][1]), cvtpk(acc[r][2], acc[r][3]));
        }
    }
}

// ---------------- aggregation 2 (64 ch bf16): 1 wave/node, lane-halves alternate edges ----------------

__global__ __launch_bounds__(256) void k_agg2(const unsigned short* __restrict__ h2b,
                                              const int* __restrict__ deg,
                                              const int* __restrict__ rowptr, const unsigned* __restrict__ csr,
                                              const float* __restrict__ b2, float* __restrict__ out) {
    int node = blockIdx.x * 4 + (threadIdx.x >> 6);
    int lane = threadIdx.x & 63;
    int l32 = lane & 31;
    const unsigned* hp = (const unsigned*)h2b;     // 32 uints per row (2 bf16 ch each)
    float dnf = (float)(deg[node] + 1);
    float di = rsqrtf(dnf);
    float wself = di * di;
    float sx = 0.f, sy = 0.f;
    if (lane < 32) {
        unsigned u = hp[(size_t)node * 32 + l32];
        sx = wself * bflo(u);
        sy = wself * bfhi(u);
    }
    int s = rowptr[node], e = rowptr[node + 1];
    int j = s + (lane >> 5);
    for (; j + 6 < e; j += 8) {
        unsigned c0 = csr[j], c1 = csr[j + 2], c2 = csr[j + 4], c3 = csr[j + 6];
        unsigned v0 = hp[(size_t)(c0 & 0x1FFFF) * 32 + l32];
        unsigned v1 = hp[(size_t)(c1 & 0x1FFFF) * 32 + l32];
        unsigned v2 = hp[(size_t)(c2 & 0x1FFFF) * 32 + l32];
        unsigned v3 = hp[(size_t)(c3 & 0x1FFFF) * 32 + l32];
        float w0 = rsqrtf(dnf * (float)((c0 >> 17) + 1));
        float w1 = rsqrtf(dnf * (float)((c1 >> 17) + 1));
        float w2 = rsqrtf(dnf * (float)((c2 >> 17) + 1));
        float w3 = rsqrtf(dnf * (float)((c3 >> 17) + 1));
        sx = fmaf(w0, bflo(v0), sx); sy = fmaf(w0, bfhi(v0), sy);
        sx = fmaf(w1, bflo(v1), sx); sy = fmaf(w1, bfhi(v1), sy);
        sx = fmaf(w2, bflo(v2), sx); sy = fmaf(w2, bfhi(v2), sy);
        sx = fmaf(w3, bflo(v3), sx); sy = fmaf(w3, bfhi(v3), sy);
    }
    for (; j + 2 < e; j += 4) {
        unsigned c0 = csr[j], c1 = csr[j + 2];
        unsigned v0 = hp[(size_t)(c0 & 0x1FFFF) * 32 + l32];
        unsigned v1 = hp[(size_t)(c1 & 0x1FFFF) * 32 + l32];
        float w0 = rsqrtf(dnf * (float)((c0 >> 17) + 1));
        float w1 = rsqrtf(dnf * (float)((c1 >> 17) + 1));
        sx = fmaf(w0, bflo(v0), sx); sy = fmaf(w0, bfhi(v0), sy);
        sx = fmaf(w1, bflo(v1), sx); sy = fmaf(w1, bfhi(v1), sy);
    }
    if (j < e) {
        unsigned c = csr[j];
        unsigned v = hp[(size_t)(c & 0x1FFFF) * 32 + l32];
        float ww = rsqrtf(dnf * (float)((c >> 17) + 1));
        sx = fmaf(ww, bflo(v), sx); sy = fmaf(ww, bfhi(v), sy);
    }
    sx += __shfl_xor(sx, 32);
    sy += __shfl_xor(sy, 32);
    if (lane < 32) {
        float2 bb = ((const float2*)b2)[l32];
        ((float2*)out)[(size_t)node * 32 + l32] = make_float2(sx + bb.x, sy + bb.y);
    }
}

// ---------------- launch ----------------

extern "C" void kernel_launch(void* const* d_in, const int* in_sizes, int n_in,
                              void* d_out, int out_size, void* d_ws, size_t ws_size,
                              hipStream_t stream) {
    const float* x     = (const float*)d_in[0];
    const int*   ei    = (const int*)d_in[1];
    const float* W1    = (const float*)d_in[2];
    const float* b1    = (const float*)d_in[3];
    const float* gamma = (const float*)d_in[4];
    const float* beta  = (const float*)d_in[5];
    const float* W2    = (const float*)d_in[6];
    const float* b2    = (const float*)d_in[7];
    const int* row = ei;          // edge_index[0]
    const int* col = ei + NE;     // edge_index[1]
    float* out = (float*)d_out;

    char* wp = (char*)d_ws;
    auto alloc = [&](size_t bytes) -> void* {
        void* p = (void*)wp;
        wp += (bytes + 255) & ~(size_t)255;
        return p;
    };
    unsigned short* h1b = (unsigned short*)alloc((size_t)NN * HID * 2);
    unsigned* aggb = (unsigned*)alloc((size_t)NN * HID * 2);
    unsigned short* h2b = (unsigned short*)alloc((size_t)NN * OUTC * 2);
    int*   deg     = (int*)alloc((size_t)NN * 4);
    float* bnsum   = (float*)alloc(HID * 4);
    float* bnsumsq = (float*)alloc(HID * 4);
    int*   rowptr  = (int*)alloc((size_t)(NN + 1) * 4);
    int*   bhist   = (int*)alloc((size_t)NBUK * NBLK * 4);
    int*   bsum2   = (int*)alloc(NSCB * 4);
    unsigned* ebuk = (unsigned*)alloc((size_t)NE * 4);
    unsigned* csr  = (unsigned*)alloc((size_t)NE * 4);
    unsigned short* W1T = (unsigned short*)alloc((size_t)HID * INC * 2);

    hipLaunchKernelGGL(k_pre,    dim3(NBLK), dim3(256), 0, stream, col, bhist, W1, W1T, bnsum, bnsumsq);
    hipLaunchKernelGGL(k_gscanA, dim3(NSCB), dim3(GS_B), 0, stream, bhist, bhist, bsum2, NBUK * NBLK);
    hipLaunchKernelGGL(k_bpart,  dim3(NBLK), dim3(256), 0, stream, row, col, bhist, bsum2, ebuk);
    hipLaunchKernelGGL(k_nprep,  dim3(NBUK), dim3(256), 0, stream, ebuk, bhist, bsum2, deg, rowptr);
    hipLaunchKernelGGL(k_bfill,  dim3(NBUK), dim3(256), 0, stream, ebuk, bhist, bsum2, rowptr, deg, csr);
    hipLaunchKernelGGL(k_gemm1m, dim3((NN + 63) / 64), dim3(256), 0, stream, x, W1T, h1b);
    hipLaunchKernelGGL(k_agg1,   dim3(NN / 4), dim3(256), 0, stream, h1b, deg, rowptr, csr, b1, aggb);
    hipLaunchKernelGGL(k_bnstats, dim3(256), dim3(256), 0, stream, aggb, bnsum, bnsumsq);
    hipLaunchKernelGGL(k_gemm2,  dim3((NN + 63) / 64), dim3(256), 0, stream, aggb, W2, bnsum, bnsumsq, gamma, beta, h2b);
    hipLaunchKernelGGL(k_agg2,   dim3(NN / 4), dim3(256), 0, stream, h2b, deg, rowptr, csr, b2, out);
}

// Round 8
// 311.302 us; speedup vs baseline: 1.5046x; 1.0055x over previous
//
#include <hip/hip_runtime.h>

#define NN 100000
#define NE 1600000
#define INC 512
#define HID 128
#define OUTC 64
#define BN_EPS 1e-5f

#define GS_B 1024
#define NSCB 98                   // scan blocks for NBUK*NBLK (=100096 <= 100352)

#define NBLK 256
#define CHUNK (NE / NBLK)         // 6250 exactly
#define BSH 8
#define NBUK ((NN + 255) >> 8)    // 391 buckets of 256 nodes

#define G1_TOTAL 1563             // ceil(NN/64)
#define G1A 704
#define G1B 288
#define G1C 571                   // 704+288+571 = 1563

#define APAD 72                   // LDS row stride in shorts (144B -> 2-way alias, free)
#define SMEM_BYTES (64 * APAD * 2 + 128 * APAD * 2)   // 27648: gemm1 As+Bs

typedef __attribute__((ext_vector_type(8))) short short8v;
typedef __attribute__((ext_vector_type(4))) float f32x4;

__device__ __forceinline__ unsigned short f2bf(float f) {
    unsigned u = __float_as_uint(f);
    u += 0x7FFFu + ((u >> 16) & 1u);     // round-to-nearest-even
    return (unsigned short)(u >> 16);
}

// packed f32x2 -> bf16x2 (RNE), D[15:0]=bf16(lo), D[31:16]=bf16(hi)
__device__ __forceinline__ unsigned cvtpk(float lo, float hi) {
    unsigned r;
    asm("v_cvt_pk_bf16_f32 %0, %1, %2" : "=v"(r) : "v"(lo), "v"(hi));
    return r;
}

__device__ __forceinline__ float bflo(unsigned u) { return __uint_as_float(u << 16); }
__device__ __forceinline__ float bfhi(unsigned u) { return __uint_as_float(u & 0xFFFF0000u); }

// scan the 98 raw block totals into an exclusive prefix, in LDS (per-block redundant)
__device__ __forceinline__ void scan_bsum(const int* __restrict__ bsum2, int* spref) {
    int tid = threadIdx.x;
    if (tid < NSCB) spref[tid] = bsum2[tid];
    __syncthreads();
    if (tid == 0) {
        int run = 0;
        #pragma unroll 1
        for (int i = 0; i < NSCB; ++i) { int t = spref[i]; spref[i] = run; run += t; }
    }
    __syncthreads();
}

// ---------------- fused: W1->bf16T + bucket histogram + BN-acc zero ----------------

__global__ __launch_bounds__(256) void k_pre(const int* __restrict__ col, int* __restrict__ bhist,
                                             const float* __restrict__ W1, unsigned short* __restrict__ W1T,
                                             float* bnsum, float* bnsumsq) {
    __shared__ int lc[NBUK];
    int tid = threadIdx.x, blk = blockIdx.x;
    int i = blk * 256 + tid;                     // 65536 W1 elements, grid is exactly 256 blocks
    W1T[(size_t)(i & 127) * INC + (i >> 7)] = f2bf(W1[i]);
    if (blk == 0 && tid < HID) { bnsum[tid] = 0.f; bnsumsq[tid] = 0.f; }
    for (int q = tid; q < NBUK; q += 256) lc[q] = 0;
    __syncthreads();
    int s = blk * CHUNK, e = s + CHUNK;
    for (int j = s + tid; j < e; j += 256)
        atomicAdd(&lc[col[j] >> BSH], 1);
    __syncthreads();
    for (int q = tid; q < NBUK; q += 256)
        bhist[q * NBLK + blk] = lc[q];
}

// generic scan: per-block exclusive prefix (in-place safe) + raw block totals
__global__ void k_gscanA(const int* __restrict__ src, int* __restrict__ dst,
                         int* __restrict__ bsum, int n) {
    __shared__ int s[GS_B];
    int tid = threadIdx.x;
    int i = blockIdx.x * GS_B + tid;
    int v = (i < n) ? src[i] : 0;
    s[tid] = v;
    __syncthreads();
    for (int off = 1; off < GS_B; off <<= 1) {
        int t = (tid >= off) ? s[tid - off] : 0;
        __syncthreads();
        s[tid] += t;
        __syncthreads();
    }
    if (i < n) dst[i] = s[tid] - v;
    if (tid == GS_B - 1) bsum[blockIdx.x] = s[tid];
}

// ---------------- device bodies for the fat kernels ----------------

// partition edges into buckets; entry = row | (local_col << 24)
__device__ void dev_bpart(char* smem, const int* __restrict__ row, const int* __restrict__ col,
                          const int* __restrict__ sb, const int* __restrict__ bsum2,
                          unsigned* __restrict__ ebuk, int blk) {
    int* lcur = (int*)smem;                       // NBUK ints
    int* spref = (int*)(smem + ((NBUK * 4 + 15) & ~15));  // NSCB ints
    int tid = threadIdx.x;
    scan_bsum(bsum2, spref);
    for (int i = tid; i < NBUK; i += 256) {
        int idx = i * NBLK + blk;
        lcur[i] = sb[idx] + spref[idx >> 10];
    }
    __syncthreads();
    int s = blk * CHUNK, e = s + CHUNK;
    for (int j = s + tid; j < e; j += 256) {
        int r = row[j], c = col[j];
        int p = atomicAdd(&lcur[c >> BSH], 1);
        ebuk[p] = (unsigned)r | ((unsigned)(c & 255) << 24);
    }
}

// per-bucket: node counts -> deg[], local exclusive scan -> rowptr[]
__device__ void dev_nprep(char* smem, const unsigned* __restrict__ ebuk,
                          const int* __restrict__ sb, const int* __restrict__ bsum2,
                          int* __restrict__ deg, int* __restrict__ rowptr, int b) {
    int* lc = (int*)smem;                         // 256
    int* sc = (int*)(smem + 1024);                // 256
    int* spref = (int*)(smem + 2048);             // NSCB
    int tid = threadIdx.x;
    scan_bsum(bsum2, spref);
    lc[tid] = 0;
    __syncthreads();
    int i0 = b * NBLK;
    int s = sb[i0] + spref[i0 >> 10];
    int e2 = (b + 1 < NBUK) ? (sb[i0 + NBLK] + spref[(i0 + NBLK) >> 10]) : NE;
    for (int j = s + tid; j < e2; j += 256)
        atomicAdd(&lc[ebuk[j] >> 24], 1);
    __syncthreads();
    int v = lc[tid];
    sc[tid] = v;
    __syncthreads();
    for (int off = 1; off < 256; off <<= 1) {
        int t = (tid >= off) ? sc[tid - off] : 0;
        __syncthreads();
        sc[tid] += t;
        __syncthreads();
    }
    int node = (b << BSH) + tid;
    if (node < NN) {
        deg[node] = v;
        rowptr[node] = s + sc[tid] - v;
    }
    if (b == NBUK - 1 && tid == 0) rowptr[NN] = NE;
}

// scatter csr entries: entry = row | (deg[row] << 17)
__device__ void dev_bfill(char* smem, const unsigned* __restrict__ ebuk,
                          const int* __restrict__ sb, const int* __restrict__ bsum2,
                          const int* __restrict__ rowptr, const int* __restrict__ deg,
                          unsigned* __restrict__ csr, int b) {
    int* lcur = (int*)smem;                       // 256
    int* spref = (int*)(smem + 1024);             // NSCB
    int tid = threadIdx.x;
    scan_bsum(bsum2, spref);
    int node0 = b << BSH;
    int node = node0 + tid;
    lcur[tid] = (node < NN) ? rowptr[node] : 0;
    __syncthreads();
    int i0 = b * NBLK;
    int s = sb[i0] + spref[i0 >> 10];
    int e2 = (b + 1 < NBUK) ? (sb[i0 + NBLK] + spref[(i0 + NBLK) >> 10]) : NE;
    for (int j = s + tid; j < e2; j += 256) {
        unsigned rc = ebuk[j];
        int li = rc >> 24;
        int r = rc & 0xFFFFFF;
        int p = atomicAdd(&lcur[li], 1);
        csr[p] = (unsigned)r | ((unsigned)deg[r] << 17);
    }
}

// GEMM1 (MFMA) block body: h1b[N,128](bf16) = bf16(x)[N,512] @ bf16(W1)[512,128]
// register-prefetch double-stage; operands swapped so lane owns 4 consecutive channels.
#define G1BK 64

__device__ void dev_gemm1(char* smem, const float* __restrict__ x,
                          const unsigned short* __restrict__ W1T,
                          unsigned short* __restrict__ h1b, int mblk) {
    unsigned short (*As)[APAD] = (unsigned short (*)[APAD])smem;
    unsigned short (*Bs)[APAD] = (unsigned short (*)[APAD])(smem + 64 * APAD * 2);
    int tid = threadIdx.x;
    int m0 = mblk * 64;
    int w = tid >> 6;
    int lane = tid & 63;

    f32x4 acc[4][2];
    #pragma unroll
    for (int mr = 0; mr < 4; ++mr)
        #pragma unroll
        for (int cb = 0; cb < 2; ++cb) acc[mr][cb] = (f32x4){0.f, 0.f, 0.f, 0.f};

    int ar = tid >> 2;
    int ak = (tid & 3) * 16;
    int arow = m0 + ar; if (arow >= NN) arow = NN - 1;
    const float* xr = x + (size_t)arow * INC;
    int br = tid >> 1;
    int bk = (tid & 1) * 32;
    const unsigned short* wr = W1T + (size_t)br * INC;

    int frow = lane & 15;
    int fk = (lane >> 4) * 8;

    float4 pv[4];
    short8v pb[4];
    #pragma unroll
    for (int q = 0; q < 4; ++q) pv[q] = *(const float4*)(xr + ak + q * 4);
    #pragma unroll
    for (int q = 0; q < 4; ++q) pb[q] = *(const short8v*)(wr + bk + q * 8);

    for (int k0 = 0; k0 < INC; k0 += G1BK) {
        #pragma unroll
        for (int q = 0; q < 4; ++q)
            *(uint2*)&As[ar][ak + q * 4] = make_uint2(cvtpk(pv[q].x, pv[q].y), cvtpk(pv[q].z, pv[q].w));
        #pragma unroll
        for (int q = 0; q < 4; ++q)
            *(short8v*)&Bs[br][bk + q * 8] = pb[q];
        __syncthreads();
        if (k0 + G1BK < INC) {
            #pragma unroll
            for (int q = 0; q < 4; ++q) pv[q] = *(const float4*)(xr + k0 + G1BK + ak + q * 4);
            #pragma unroll
            for (int q = 0; q < 4; ++q) pb[q] = *(const short8v*)(wr + k0 + G1BK + bk + q * 8);
        }
        #pragma unroll
        for (int kk = 0; kk < G1BK; kk += 32) {
            short8v a[4], b[2];
            #pragma unroll
            for (int mr = 0; mr < 4; ++mr)
                a[mr] = *(const short8v*)&As[16 * mr + frow][kk + fk];   // x nodes (B operand)
            #pragma unroll
            for (int cb = 0; cb < 2; ++cb)
                b[cb] = *(const short8v*)&Bs[32 * w + 16 * cb + frow][kk + fk];  // W channels (A operand)
            #pragma unroll
            for (int mr = 0; mr < 4; ++mr)
                #pragma unroll
                for (int cb = 0; cb < 2; ++cb)
                    acc[mr][cb] = __builtin_amdgcn_mfma_f32_16x16x32_bf16(b[cb], a[mr], acc[mr][cb], 0, 0, 0);
        }
        __syncthreads();
    }
    int ncol = lane & 15;
    int r4 = (lane >> 4) * 4;
    #pragma unroll
    for (int mr = 0; mr < 4; ++mr) {
        int node = m0 + 16 * mr + ncol;
        if (node < NN) {
            #pragma unroll
            for (int cb = 0; cb < 2; ++cb) {
                int ch = 32 * w + 16 * cb + r4;
                *(uint2*)&h1b[(size_t)node * HID + ch] =
                    make_uint2(cvtpk(acc[mr][cb][0], acc[mr][cb][1]),
                               cvtpk(acc[mr][cb][2], acc[mr][cb][3]));
            }
        }
    }
}

// ---------------- fat kernels: CSR stage + gemm1 slice ----------------

__global__ __launch_bounds__(256) void k_fuse1(const int* __restrict__ row, const int* __restrict__ col,
                                               const int* __restrict__ sb, const int* __restrict__ bsum2,
                                               unsigned* __restrict__ ebuk,
                                               const float* __restrict__ x,
                                               const unsigned short* __restrict__ W1T,
                                               unsigned short* __restrict__ h1b) {
    __shared__ __align__(16) char smem[SMEM_BYTES];
    if (blockIdx.x < NBLK) dev_bpart(smem, row, col, sb, bsum2, ebuk, blockIdx.x);
    else                   dev_gemm1(smem, x, W1T, h1b, blockIdx.x - NBLK);
}

__global__ __launch_bounds__(256) void k_fuse2(const unsigned* __restrict__ ebuk,
                                               const int* __restrict__ sb, const int* __restrict__ bsum2,
                                               int* __restrict__ deg, int* __restrict__ rowptr,
                                               const float* __restrict__ x,
                                               const unsigned short* __restrict__ W1T,
                                               unsigned short* __restrict__ h1b) {
    __shared__ __align__(16) char smem[SMEM_BYTES];
    if (blockIdx.x < NBUK) dev_nprep(smem, ebuk, sb, bsum2, deg, rowptr, blockIdx.x);
    else                   dev_gemm1(smem, x, W1T, h1b, blockIdx.x - NBUK + G1A);
}

__global__ __launch_bounds__(256) void k_fuse3(const unsigned* __restrict__ ebuk,
                                               const int* __restrict__ sb, const int* __restrict__ bsum2,
                                               const int* __restrict__ rowptr, const int* __restrict__ deg,
                                               unsigned* __restrict__ csr,
                                               const float* __restrict__ x,
                                               const unsigned short* __restrict__ W1T,
                                               unsigned short* __restrict__ h1b) {
    __shared__ __align__(16) char smem[SMEM_BYTES];
    if (blockIdx.x < NBUK) dev_bfill(smem, ebuk, sb, bsum2, rowptr, deg, csr, blockIdx.x);
    else                   dev_gemm1(smem, x, W1T, h1b, blockIdx.x - NBUK + G1A + G1B);
}

// ---------------- aggregation 1 (128 ch bf16 -> bf16): 1 wave/node, 8-deep unroll ----------------

__global__ __launch_bounds__(256) void k_agg1(const unsigned short* __restrict__ h1b,
                                              const int* __restrict__ rowptr, const unsigned* __restrict__ csr,
                                              const float* __restrict__ b1, unsigned* __restrict__ aggb) {
    int node = blockIdx.x * 4 + (threadIdx.x >> 6);
    int lane = threadIdx.x & 63;
    const unsigned* hp = (const unsigned*)h1b;     // 64 uints per row (2 bf16 ch each)
    size_t base = (size_t)node * 64 + lane;
    int s = rowptr[node], e = rowptr[node + 1];
    float dnf = (float)(e - s + 1);
    float di = rsqrtf(dnf);
    float wself = di * di;
    unsigned hv = hp[base];
    float sx = wself * bflo(hv);
    float sy = wself * bfhi(hv);
    int j = s;
    for (; j + 8 <= e; j += 8) {
        unsigned c0 = csr[j],     c1 = csr[j + 1], c2 = csr[j + 2], c3 = csr[j + 3];
        unsigned c4 = csr[j + 4], c5 = csr[j + 5], c6 = csr[j + 6], c7 = csr[j + 7];
        unsigned v0 = hp[(size_t)(c0 & 0x1FFFF) * 64 + lane];
        unsigned v1 = hp[(size_t)(c1 & 0x1FFFF) * 64 + lane];
        unsigned v2 = hp[(size_t)(c2 & 0x1FFFF) * 64 + lane];
        unsigned v3 = hp[(size_t)(c3 & 0x1FFFF) * 64 + lane];
        unsigned v4 = hp[(size_t)(c4 & 0x1FFFF) * 64 + lane];
        unsigned v5 = hp[(size_t)(c5 & 0x1FFFF) * 64 + lane];
        unsigned v6 = hp[(size_t)(c6 & 0x1FFFF) * 64 + lane];
        unsigned v7 = hp[(size_t)(c7 & 0x1FFFF) * 64 + lane];
        float w0 = rsqrtf(dnf * (float)((c0 >> 17) + 1));
        float w1 = rsqrtf(dnf * (float)((c1 >> 17) + 1));
        float w2 = rsqrtf(dnf * (float)((c2 >> 17) + 1));
        float w3 = rsqrtf(dnf * (float)((c3 >> 17) + 1));
        float w4 = rsqrtf(dnf * (float)((c4 >> 17) + 1));
        float w5 = rsqrtf(dnf * (float)((c5 >> 17) + 1));
        float w6 = rsqrtf(dnf * (float)((c6 >> 17) + 1));
        float w7 = rsqrtf(dnf * (float)((c7 >> 17) + 1));
        sx = fmaf(w0, bflo(v0), sx); sy = fmaf(w0, bfhi(v0), sy);
        sx = fmaf(w1, bflo(v1), sx); sy = fmaf(w1, bfhi(v1), sy);
        sx = fmaf(w2, bflo(v2), sx); sy = fmaf(w2, bfhi(v2), sy);
        sx = fmaf(w3, bflo(v3), sx); sy = fmaf(w3, bfhi(v3), sy);
        sx = fmaf(w4, bflo(v4), sx); sy = fmaf(w4, bfhi(v4), sy);
        sx = fmaf(w5, bflo(v5), sx); sy = fmaf(w5, bfhi(v5), sy);
        sx = fmaf(w6, bflo(v6), sx); sy = fmaf(w6, bfhi(v6), sy);
        sx = fmaf(w7, bflo(v7), sx); sy = fmaf(w7, bfhi(v7), sy);
    }
    for (; j + 4 <= e; j += 4) {
        unsigned c0 = csr[j], c1 = csr[j + 1], c2 = csr[j + 2], c3 = csr[j + 3];
        unsigned v0 = hp[(size_t)(c0 & 0x1FFFF) * 64 + lane];
        unsigned v1 = hp[(size_t)(c1 & 0x1FFFF) * 64 + lane];
        unsigned v2 = hp[(size_t)(c2 & 0x1FFFF) * 64 + lane];
        unsigned v3 = hp[(size_t)(c3 & 0x1FFFF) * 64 + lane];
        float w0 = rsqrtf(dnf * (float)((c0 >> 17) + 1));
        float w1 = rsqrtf(dnf * (float)((c1 >> 17) + 1));
        float w2 = rsqrtf(dnf * (float)((c2 >> 17) + 1));
        float w3 = rsqrtf(dnf * (float)((c3 >> 17) + 1));
        sx = fmaf(w0, bflo(v0), sx); sy = fmaf(w0, bfhi(v0), sy);
        sx = fmaf(w1, bflo(v1), sx); sy = fmaf(w1, bfhi(v1), sy);
        sx = fmaf(w2, bflo(v2), sx); sy = fmaf(w2, bfhi(v2), sy);
        sx = fmaf(w3, bflo(v3), sx); sy = fmaf(w3, bfhi(v3), sy);
    }
    for (; j < e; ++j) {
        unsigned c = csr[j];
        unsigned v = hp[(size_t)(c & 0x1FFFF) * 64 + lane];
        float ww = rsqrtf(dnf * (float)((c >> 17) + 1));
        sx = fmaf(ww, bflo(v), sx); sy = fmaf(ww, bfhi(v), sy);
    }
    float2 bb = ((const float2*)b1)[lane];
    aggb[base] = cvtpk(sx + bb.x, sy + bb.y);
}

// ---------------- BN stats (from bf16 agg) ----------------

__global__ __launch_bounds__(256) void k_bnstats(const unsigned* __restrict__ aggb,
                                                 float* __restrict__ bnsum, float* __restrict__ bnsumsq) {
    __shared__ float4 ss[256], sq[256];
    int g = threadIdx.x & 31;          // 4-channel group: channels 4g..4g+3
    int h = threadIdx.x >> 5;          // 0..7 row offset
    float4 fs = make_float4(0.f, 0.f, 0.f, 0.f);
    float4 fq = make_float4(0.f, 0.f, 0.f, 0.f);
    int rows_per_block = (NN + gridDim.x - 1) / gridDim.x;
    int r0 = blockIdx.x * rows_per_block;
    int r1 = r0 + rows_per_block; if (r1 > NN) r1 = NN;
    for (int r = r0 + h; r < r1; r += 8) {
        uint2 u = *(const uint2*)(aggb + (size_t)r * 64 + 2 * g);
        float a0 = bflo(u.x), a1 = bfhi(u.x), a2 = bflo(u.y), a3 = bfhi(u.y);
        fs.x += a0; fs.y += a1; fs.z += a2; fs.w += a3;
        fq.x += a0 * a0; fq.y += a1 * a1; fq.z += a2 * a2; fq.w += a3 * a3;
    }
    ss[threadIdx.x] = fs; sq[threadIdx.x] = fq;
    __syncthreads();
    if (threadIdx.x < 32) {
        float4 as = ss[threadIdx.x], aq = sq[threadIdx.x];
        #pragma unroll
        for (int k = 1; k < 8; ++k) {
            float4 bs = ss[k * 32 + threadIdx.x], bq = sq[k * 32 + threadIdx.x];
            as.x += bs.x; as.y += bs.y; as.z += bs.z; as.w += bs.w;
            aq.x += bq.x; aq.y += bq.y; aq.z += bq.z; aq.w += bq.w;
        }
        atomicAdd(&bnsum[4 * g + 0], as.x); atomicAdd(&bnsum[4 * g + 1], as.y);
        atomicAdd(&bnsum[4 * g + 2], as.z); atomicAdd(&bnsum[4 * g + 3], as.w);
        atomicAdd(&bnsumsq[4 * g + 0], aq.x); atomicAdd(&bnsumsq[4 * g + 1], aq.y);
        atomicAdd(&bnsumsq[4 * g + 2], aq.z); atomicAdd(&bnsumsq[4 * g + 3], aq.w);
    }
}

// ---------------- GEMM2 (+inline BN finalize): h2b = relu(bn(aggb)) @ W2 ----------------

__global__ __launch_bounds__(256) void k_gemm2(const unsigned* __restrict__ aggb, const float* __restrict__ W2,
                                               const float* __restrict__ bnsum, const float* __restrict__ bnsumsq,
                                               const float* __restrict__ gamma, const float* __restrict__ beta,
                                               unsigned short* __restrict__ h2b) {
    __shared__ float As2[32][66];
    __shared__ float Bs2[32][OUTC];
    __shared__ float bnsc[HID], bnsh[HID];
    int tid = threadIdx.x;
    if (tid < HID) {
        float mu = bnsum[tid] / (float)NN;
        float var = bnsumsq[tid] / (float)NN - mu * mu;
        float sc = gamma[tid] * rsqrtf(var + BN_EPS);
        bnsc[tid] = sc;
        bnsh[tid] = beta[tid] - mu * sc;
    }
    __syncthreads();
    int m0 = blockIdx.x * 64;
    int tx = tid & 15, ty = tid >> 4;
    float acc[4][4];
    #pragma unroll
    for (int r = 0; r < 4; ++r)
        #pragma unroll
        for (int c = 0; c < 4; ++c) acc[r][c] = 0.f;

    int am = tid >> 3;          // 0..31
    int ak = (tid & 7) * 4;     // 0..28
    int bk = tid >> 4;          // 0..15
    int bc = (tid & 15) * 4;    // 0..60

    for (int k0 = 0; k0 < HID; k0 += 32) {
        #pragma unroll
        for (int h = 0; h < 2; ++h) {
            int m = am + h * 32;
            int rowi = m0 + m; if (rowi >= NN) rowi = NN - 1;
            uint2 u = *(const uint2*)(aggb + (size_t)rowi * 64 + ((k0 + ak) >> 1));
            float4 sc = *(const float4*)&bnsc[k0 + ak];
            float4 sh = *(const float4*)&bnsh[k0 + ak];
            As2[ak + 0][m] = fmaxf(fmaf(bflo(u.x), sc.x, sh.x), 0.f);
            As2[ak + 1][m] = fmaxf(fmaf(bfhi(u.x), sc.y, sh.y), 0.f);
            As2[ak + 2][m] = fmaxf(fmaf(bflo(u.y), sc.z, sh.z), 0.f);
            As2[ak + 3][m] = fmaxf(fmaf(bfhi(u.y), sc.w, sh.w), 0.f);
        }
        #pragma unroll
        for (int h = 0; h < 2; ++h) {
            int k = bk + h * 16;
            *(float4*)&Bs2[k][bc] = *(const float4*)(W2 + (size_t)(k0 + k) * OUTC + bc);
        }
        __syncthreads();
        #pragma unroll
        for (int k = 0; k < 32; ++k) {
            float a[4];
            #pragma unroll
            for (int r = 0; r < 4; ++r) a[r] = As2[k][ty * 4 + r];
            float4 b = *(const float4*)&Bs2[k][tx * 4];
            #pragma unroll
            for (int r = 0; r < 4; ++r) {
                acc[r][0] = fmaf(a[r], b.x, acc[r][0]);
                acc[r][1] = fmaf(a[r], b.y, acc[r][1]);
                acc[r][2] = fmaf(a[r], b.z, acc[r][2]);
                acc[r][3] = fmaf(a[r], b.w, acc[r][3]);
            }
        }
        __syncthreads();
    }
    #pragma unroll
    for (int r = 0; r < 4; ++r) {
        int m = m0 + ty * 4 + r;
        if (m < NN) {
            *(uint2*)(h2b + (size_t)m * OUTC + tx * 4) =
                make_uint2(cvtpk(acc[r][0], acc[r][1]), cvtpk(acc[r][2], acc[r][3]));
        }
    }
}

// ---------------- aggregation 2 (64 ch bf16): 1 wave/node, lane-halves alternate edges ----------------

__global__ __launch_bounds__(256) void k_agg2(const unsigned short* __restrict__ h2b,
                                              const int* __restrict__ rowptr, const unsigned* __restrict__ csr,
                                              const float* __restrict__ b2, float* __restrict__ out) {
    int node = blockIdx.x * 4 + (threadIdx.x >> 6);
    int lane = threadIdx.x & 63;
    int l32 = lane & 31;
    const unsigned* hp = (const unsigned*)h2b;     // 32 uints per row (2 bf16 ch each)
    int s = rowptr[node], e = rowptr[node + 1];
    float dnf = (float)(e - s + 1);
    float di = rsqrtf(dnf);
    float wself = di * di;
    float sx = 0.f, sy = 0.f;
    if (lane < 32) {
        unsigned u = hp[(size_t)node * 32 + l32];
        sx = wself * bflo(u);
        sy = wself * bfhi(u);
    }
    int j = s + (lane >> 5);
    for (; j + 6 < e; j += 8) {
        unsigned c0 = csr[j], c1 = csr[j + 2], c2 = csr[j + 4], c3 = csr[j + 6];
        unsigned v0 = hp[(size_t)(c0 & 0x1FFFF) * 32 + l32];
        unsigned v1 = hp[(size_t)(c1 & 0x1FFFF) * 32 + l32];
        unsigned v2 = hp[(size_t)(c2 & 0x1FFFF) * 32 + l32];
        unsigned v3 = hp[(size_t)(c3 & 0x1FFFF) * 32 + l32];
        float w0 = rsqrtf(dnf * (float)((c0 >> 17) + 1));
        float w1 = rsqrtf(dnf * (float)((c1 >> 17) + 1));
        float w2 = rsqrtf(dnf * (float)((c2 >> 17) + 1));
        float w3 = rsqrtf(dnf * (float)((c3 >> 17) + 1));
        sx = fmaf(w0, bflo(v0), sx); sy = fmaf(w0, bfhi(v0), sy);
        sx = fmaf(w1, bflo(v1), sx); sy = fmaf(w1, bfhi(v1), sy);
        sx = fmaf(w2, bflo(v2), sx); sy = fmaf(w2, bfhi(v2), sy);
        sx = fmaf(w3, bflo(v3), sx); sy = fmaf(w3, bfhi(v3), sy);
    }
    for (; j + 2 < e; j += 4) {
        unsigned c0 = csr[j], c1 = csr[j + 2];
        unsigned v0 = hp[(size_t)(c0 & 0x1FFFF) * 32 + l32];
        unsigned v1 = hp[(size_t)(c1 & 0x1FFFF) * 32 + l32];
        float w0 = rsqrtf(dnf * (float)((c0 >> 17) + 1));
        float w1 = rsqrtf(dnf * (float)((c1 >> 17) + 1));
        sx = fmaf(w0, bflo(v0), sx); sy = fmaf(w0, bfhi(v0), sy);
        sx = fmaf(w1, bflo(v1), sx); sy = fmaf(w1, bfhi(v1), sy);
    }
    if (j < e) {
        unsigned c = csr[j];
        unsigned v = hp[(size_t)(c & 0x1FFFF) * 32 + l32];
        float ww = rsqrtf(dnf * (float)((c >> 17) + 1));
        sx = fmaf(ww, bflo(v), sx); sy = fmaf(ww, bfhi(v), sy);
    }
    sx += __shfl_xor(sx, 32);
    sy += __shfl_xor(sy, 32);
    if (lane < 32) {
        float2 bb = ((const float2*)b2)[l32];
        ((float2*)out)[(size_t)node * 32 + l32] = make_float2(sx + bb.x, sy + bb.y);
    }
}

// ---------------- launch ----------------

extern "C" void kernel_launch(void* const* d_in, const int* in_sizes, int n_in,
                              void* d_out, int out_size, void* d_ws, size_t ws_size,
                              hipStream_t stream) {
    const float* x     = (const float*)d_in[0];
    const int*   ei    = (const int*)d_in[1];
    const float* W1    = (const float*)d_in[2];
    const float* b1    = (const float*)d_in[3];
    const float* gamma = (const float*)d_in[4];
    const float* beta  = (const float*)d_in[5];
    const float* W2    = (const float*)d_in[6];
    const float* b2    = (const float*)d_in[7];
    const int* row = ei;          // edge_index[0]
    const int* col = ei + NE;     // edge_index[1]
    float* out = (float*)d_out;

    char* wp = (char*)d_ws;
    auto alloc = [&](size_t bytes) -> void* {
        void* p = (void*)wp;
        wp += (bytes + 255) & ~(size_t)255;
        return p;
    };
    unsigned short* h1b = (unsigned short*)alloc((size_t)NN * HID * 2);
    unsigned* aggb = (unsigned*)alloc((size_t)NN * HID * 2);
    unsigned short* h2b = (unsigned short*)alloc((size_t)NN * OUTC * 2);
    int*   deg     = (int*)alloc((size_t)NN * 4);
    float* bnsum   = (float*)alloc(HID * 4);
    float* bnsumsq = (float*)alloc(HID * 4);
    int*   rowptr  = (int*)alloc((size_t)(NN + 1) * 4);
    int*   bhist   = (int*)alloc((size_t)NBUK * NBLK * 4);
    int*   bsum2   = (int*)alloc(NSCB * 4);
    unsigned* ebuk = (unsigned*)alloc((size_t)NE * 4);
    unsigned* csr  = (unsigned*)alloc((size_t)NE * 4);
    unsigned short* W1T = (unsigned short*)alloc((size_t)HID * INC * 2);

    hipLaunchKernelGGL(k_pre,    dim3(NBLK), dim3(256), 0, stream, col, bhist, W1, W1T, bnsum, bnsumsq);
    hipLaunchKernelGGL(k_gscanA, dim3(NSCB), dim3(GS_B), 0, stream, bhist, bhist, bsum2, NBUK * NBLK);
    hipLaunchKernelGGL(k_fuse1,  dim3(NBLK + G1A), dim3(256), 0, stream, row, col, bhist, bsum2, ebuk, x, W1T, h1b);
    hipLaunchKernelGGL(k_fuse2,  dim3(NBUK + G1B), dim3(256), 0, stream, ebuk, bhist, bsum2, deg, rowptr, x, W1T, h1b);
    hipLaunchKernelGGL(k_fuse3,  dim3(NBUK + G1C), dim3(256), 0, stream, ebuk, bhist, bsum2, rowptr, deg, csr, x, W1T, h1b);
    hipLaunchKernelGGL(k_agg1,   dim3(NN / 4), dim3(256), 0, stream, h1b, rowptr, csr, b1, aggb);
    hipLaunchKernelGGL(k_bnstats, dim3(256), dim3(256), 0, stream, aggb, bnsum, bnsumsq);
    hipLaunchKernelGGL(k_gemm2,  dim3((NN + 63) / 64), dim3(256), 0, stream, aggb, W2, bnsum, bnsumsq, gamma, beta, h2b);
    hipLaunchKernelGGL(k_agg2,   dim3(NN / 4), dim3(256), 0, stream, h2b, rowptr, csr, b2, out);
}